// Round 5
// baseline (434.253 us; speedup 1.0000x reference)
//
#include <hip/hip_runtime.h>
#include <math.h>

#define TOKENS 2048
#define DIM 1024
#define NHEADS 16
#define HEADDIM 64
#define NEXP 32
#define EDIM 128
#define TOPK 8
#define DSHARED 2048
#define RSF_ 2.5f
#define EPS_ 1e-6f
#define MAXTILES 288   // sum_e ceil(cnt_e/64) <= 16384/64 + 32

using bf8  = __attribute__((ext_vector_type(8))) short;   // 8 bf16 in 4 VGPRs
using f32x4 = __attribute__((ext_vector_type(4))) float;  // MFMA accumulator

__device__ __forceinline__ short f2bf(float f) {
    unsigned u = __float_as_uint(f);
    unsigned r = (u + 0x7fffu + ((u >> 16) & 1u)) >> 16;
    return (short)r;
}
__device__ __forceinline__ float bf2f(short s) {
    return __uint_as_float(((unsigned)(unsigned short)s) << 16);
}

// Direct global->LDS DMA, 16B per lane. LDS dest = wave-uniform base + lane*16.
// Global source address is PER-LANE -> gathered rows work.
__device__ __forceinline__ void async16(const short* g, const short* l) {
    __builtin_amdgcn_global_load_lds(
        (const __attribute__((address_space(1))) void*)(unsigned long long)g,
        (__attribute__((address_space(3))) void*)(unsigned)(unsigned long long)l,
        16, 0, 0);
}

// ---------------- RMSNorm: one block per token, bf16 output ----------------
__global__ __launch_bounds__(256) void rmsnorm_kernel(const float* __restrict__ x,
                                                      const float* __restrict__ w,
                                                      short* __restrict__ out) {
    int row = blockIdx.x;
    const float* xr = x + (long long)row * DIM;
    int t = threadIdx.x;
    float4 xv = ((const float4*)xr)[t];
    float ss = xv.x*xv.x + xv.y*xv.y + xv.z*xv.z + xv.w*xv.w;
    #pragma unroll
    for (int off = 32; off; off >>= 1) ss += __shfl_down(ss, off);
    __shared__ float warps[4];
    if ((t & 63) == 0) warps[t >> 6] = ss;
    __syncthreads();
    float tot = warps[0] + warps[1] + warps[2] + warps[3];
    float scale = rsqrtf(tot / (float)DIM + EPS_);
    float4 wv = ((const float4*)w)[t];
    short4 o;
    o.x = f2bf(xv.x * scale * wv.x);
    o.y = f2bf(xv.y * scale * wv.y);
    o.z = f2bf(xv.z * scale * wv.z);
    o.w = f2bf(xv.w * scale * wv.w);
    ((short4*)(out + (long long)row * DIM))[t] = o;
}

// ---------------- Transpose + convert: fp32 in[K][N] -> bf16 out[N][K] ----------------
__global__ __launch_bounds__(256) void tconv(const float* __restrict__ in, long long sin,
                                             short* __restrict__ out, long long sout,
                                             int K, int N) {
    in  += (long long)blockIdx.z * sin;
    out += (long long)blockIdx.z * sout;
    __shared__ float t[32][33];
    int n0 = blockIdx.x * 32, k0 = blockIdx.y * 32;
    int tx = threadIdx.x & 31, ty = threadIdx.x >> 5;  // ty 0..7
    #pragma unroll
    for (int r = ty; r < 32; r += 8)
        t[r][tx] = in[(long long)(k0 + r) * N + n0 + tx];
    __syncthreads();
    #pragma unroll
    for (int r = ty; r < 32; r += 8)
        out[(long long)(n0 + r) * K + k0 + tx] = f2bf(t[tx][r]);
}

// W2 [e][d][h] fp32 -> bf16 [d][(e*128+h)]
__global__ void w2conv(const float* __restrict__ in, short* __restrict__ out) {
    long long i = (long long)blockIdx.x * 256 + threadIdx.x;  // 4M
    int e = (int)(i >> 17);
    int d = (int)(i >> 7) & 1023;
    int h = (int)(i & 127);
    out[(long long)d * (NEXP * EDIM) + e * EDIM + h] = f2bf(in[i]);
}

// W0/W1 [e][k=0..1023][c=0..127] fp32 -> wgu'[e] rows rr=(c>>4)*32+half*16+(c&15), col k
__global__ __launch_bounds__(256) void guconv(const float* __restrict__ ex,
                                              short* __restrict__ wgu) {
    int z = blockIdx.z;            // 0..63
    int e = z & 31, hf = z >> 5;
    const float* in = ex + (long long)hf * (NEXP * DIM * EDIM) + (long long)e * (DIM * EDIM);
    short* outp = wgu + (long long)e * (256 * 1024);
    __shared__ float t[32][33];
    int n0 = blockIdx.x * 32, k0 = blockIdx.y * 32;
    int tx = threadIdx.x & 31, ty = threadIdx.x >> 5;
    #pragma unroll
    for (int r = ty; r < 32; r += 8)
        t[r][tx] = in[(long long)(k0 + r) * EDIM + n0 + tx];
    __syncthreads();
    #pragma unroll
    for (int r = ty; r < 32; r += 8) {
        int c = n0 + r;
        int rr = ((c >> 4) << 5) + hf * 16 + (c & 15);
        outp[(long long)rr * 1024 + k0 + tx] = f2bf(t[tx][r]);
    }
}

// w_up [1024][4096] fp32 -> wupt' interleaved rows: for logical col n:
// half=n>>11, c2=n&2047, b=c2>>7, cl=c2&127 -> rr = b*256+(cl>>4)*32+half*16+(cl&15)
__global__ __launch_bounds__(256) void upconv(const float* __restrict__ in,
                                              short* __restrict__ outp) {
    __shared__ float t[32][33];
    int n0 = blockIdx.x * 32, k0 = blockIdx.y * 32;
    int tx = threadIdx.x & 31, ty = threadIdx.x >> 5;
    #pragma unroll
    for (int r = ty; r < 32; r += 8)
        t[r][tx] = in[(long long)(k0 + r) * (2 * DSHARED) + n0 + tx];
    __syncthreads();
    #pragma unroll
    for (int r = ty; r < 32; r += 8) {
        int n = n0 + r;
        int hf = n >> 11, c2 = n & 2047;
        int rr = ((c2 >> 7) << 8) + (((c2 & 127) >> 4) << 5) + hf * 16 + (c2 & 15);
        outp[(long long)rr * 1024 + k0 + tx] = f2bf(t[tx][r]);
    }
}

// ---------------- bf16 MFMA GEMM: C[M][N] = A[M][K] @ Bt[N][K]^T ----------------
// 128x128 tile, BK=64, XOR-swizzled LDS, async global->LDS staging, double-buffered.
// MODE 2: bf16 store, z = batch.
// MODE 3: f32 store, z = K-split slice (sC = slice stride). No atomics.
// MODE 4: f32 read+add+store, z = K-split slice (block-exclusive tiles).
template<int MODE>
__global__ __launch_bounds__(256) void gemm_bf16(const short* __restrict__ A, int lda, long long sA,
                                                 const short* __restrict__ Bt, int ldb, long long sBt,
                                                 void* __restrict__ Cv, int ldc, long long sC,
                                                 int M, int N, int K) {
    int koff = 0, Ksub = K;
    if (MODE >= 3) {
        Ksub = K / gridDim.z;
        koff = blockIdx.z * Ksub;
    } else {
        A  += (long long)blockIdx.z * sA;
        Bt += (long long)blockIdx.z * sBt;
    }
    float* Cf = (float*)Cv;
    short* Cs = (short*)Cv;
    Cf += (long long)blockIdx.z * sC;
    Cs += (long long)blockIdx.z * sC;
    const int m0 = blockIdx.y * 128, n0 = blockIdx.x * 128;
    __shared__ short As[2][128 * 64];
    __shared__ short Bs[2][128 * 64];
    const int tid = threadIdx.x, lane = tid & 63, w = tid >> 6;
    const int wm = (w >> 1) * 64, wn = (w & 1) * 64;
    const int drow = lane >> 3;
    const int dcol = ((lane & 7) ^ drow) * 8;
    const short* ag = A + (long long)(m0 + w * 32 + drow) * lda + koff + dcol;
    const short* bg = Bt + (long long)(n0 + w * 32 + drow) * ldb + koff + dcol;
    f32x4 acc[4][4];
    #pragma unroll
    for (int i = 0; i < 4; ++i)
        #pragma unroll
        for (int j = 0; j < 4; ++j) { f32x4 z = {0.f, 0.f, 0.f, 0.f}; acc[i][j] = z; }
    const int ra = lane & 15, quad = lane >> 4;
    const int fs0 = ((quad + 0) ^ (ra & 7)) * 8;
    const int fs1 = ((quad + 4) ^ (ra & 7)) * 8;
    {
        const short* lA = As[0] + w * 32 * 64;
        const short* lB = Bs[0] + w * 32 * 64;
        #pragma unroll
        for (int c = 0; c < 4; ++c) {
            async16(ag + (long long)(c * 8) * lda, lA + c * 512);
            async16(bg + (long long)(c * 8) * ldb, lB + c * 512);
        }
    }
    int cur = 0;
    for (int k0 = 0; k0 < Ksub; k0 += 64) {
        __syncthreads();
        if (k0 + 64 < Ksub) {
            const int nxt = cur ^ 1;
            const short* lA = As[nxt] + w * 32 * 64;
            const short* lB = Bs[nxt] + w * 32 * 64;
            #pragma unroll
            for (int c = 0; c < 4; ++c) {
                async16(ag + (long long)(c * 8) * lda + k0 + 64, lA + c * 512);
                async16(bg + (long long)(c * 8) * ldb + k0 + 64, lB + c * 512);
            }
        }
        const short* cA = As[cur];
        const short* cB = Bs[cur];
        #pragma unroll
        for (int h = 0; h < 2; ++h) {
            const int fs = h ? fs1 : fs0;
            bf8 af[4], bfv[4];
            #pragma unroll
            for (int i = 0; i < 4; ++i) af[i]  = *(const bf8*)(cA + (wm + i * 16 + ra) * 64 + fs);
            #pragma unroll
            for (int j = 0; j < 4; ++j) bfv[j] = *(const bf8*)(cB + (wn + j * 16 + ra) * 64 + fs);
            #pragma unroll
            for (int i = 0; i < 4; ++i)
                #pragma unroll
                for (int j = 0; j < 4; ++j)
                    acc[i][j] = __builtin_amdgcn_mfma_f32_16x16x32_bf16(af[i], bfv[j], acc[i][j], 0, 0, 0);
        }
        cur ^= 1;
    }
    const int cr = quad * 4, cc = ra;
    #pragma unroll
    for (int i = 0; i < 4; ++i) {
        #pragma unroll
        for (int r = 0; r < 4; ++r) {
            int row = m0 + wm + i * 16 + cr + r;
            long long base = (long long)row * ldc + n0 + wn + cc;
            #pragma unroll
            for (int j = 0; j < 4; ++j) {
                float v = acc[i][j][r];
                if (MODE == 2) Cs[base + j * 16] = f2bf(v);
                if (MODE == 3) Cf[base + j * 16] = v;
                if (MODE == 4) Cf[base + j * 16] = Cf[base + j * 16] + v;
            }
        }
    }
}

// ---------------- Fused GEMM + gated activation (dense; shared-expert up-proj) ----
// Tile: 64 M-rows x 256 weight rows, BK=64, double-buffered (R2-proven).
template<bool SCALED>
__global__ __launch_bounds__(256) void gemm_act(const short* __restrict__ A, int lda,
                                                const short* __restrict__ Bt, long long sBt,
                                                short* __restrict__ Ct, int ldct,
                                                const float* __restrict__ wr) {
    const short* Bp = Bt + (long long)blockIdx.z * sBt + (long long)blockIdx.x * (256 * 1024);
    const int cb = (blockIdx.z * gridDim.x + blockIdx.x) * 128;
    const int m0 = blockIdx.y * 64;
    __shared__ short As[2][64 * 64];
    __shared__ short Bs[2][256 * 64];
    const int tid = threadIdx.x, lane = tid & 63, w = tid >> 6;
    const int wm = (w >> 1) * 32, wn = (w & 1) * 128;
    const int drow = lane >> 3;
    const int dcol = ((lane & 7) ^ drow) * 8;
    const short* ag = A + (long long)(m0 + w * 16 + drow) * lda + dcol;
    const short* bg = Bp + (long long)(w * 64 + drow) * 1024 + dcol;
    f32x4 acc[2][8];
    #pragma unroll
    for (int i = 0; i < 2; ++i)
        #pragma unroll
        for (int j = 0; j < 8; ++j) { f32x4 z = {0.f, 0.f, 0.f, 0.f}; acc[i][j] = z; }
    const int ra = lane & 15, quad = lane >> 4;
    const int fs0 = ((quad + 0) ^ (ra & 7)) * 8;
    const int fs1 = ((quad + 4) ^ (ra & 7)) * 8;
    {
        const short* lA = As[0] + w * 16 * 64;
        const short* lB = Bs[0] + w * 64 * 64;
        async16(ag, lA);
        async16(ag + (long long)8 * lda, lA + 512);
        #pragma unroll
        for (int c = 0; c < 8; ++c)
            async16(bg + (long long)(c * 8) * 1024, lB + c * 512);
    }
    int cur = 0;
    for (int k0 = 0; k0 < 1024; k0 += 64) {
        __syncthreads();
        if (k0 + 64 < 1024) {
            const int nxt = cur ^ 1;
            const short* lA = As[nxt] + w * 16 * 64;
            const short* lB = Bs[nxt] + w * 64 * 64;
            async16(ag + k0 + 64, lA);
            async16(ag + (long long)8 * lda + k0 + 64, lA + 512);
            #pragma unroll
            for (int c = 0; c < 8; ++c)
                async16(bg + (long long)(c * 8) * 1024 + k0 + 64, lB + c * 512);
        }
        const short* cA = As[cur];
        const short* cB = Bs[cur];
        #pragma unroll
        for (int h = 0; h < 2; ++h) {
            const int fs = h ? fs1 : fs0;
            bf8 af0 = *(const bf8*)(cA + (wm + ra) * 64 + fs);
            bf8 af1 = *(const bf8*)(cA + (wm + 16 + ra) * 64 + fs);
            #pragma unroll
            for (int j = 0; j < 8; ++j) {
                bf8 bv = *(const bf8*)(cB + (wn + j * 16 + ra) * 64 + fs);
                acc[0][j] = __builtin_amdgcn_mfma_f32_16x16x32_bf16(af0, bv, acc[0][j], 0, 0, 0);
                acc[1][j] = __builtin_amdgcn_mfma_f32_16x16x32_bf16(af1, bv, acc[1][j], 0, 0, 0);
            }
        }
        cur ^= 1;
    }
    #pragma unroll
    for (int i = 0; i < 2; ++i)
        #pragma unroll
        for (int r = 0; r < 4; ++r) {
            int token = m0 + wm + i * 16 + quad * 4 + r;
            float scale = SCALED ? wr[token * NEXP + blockIdx.z] : 1.0f;
            #pragma unroll
            for (int jp = 0; jp < 4; ++jp) {
                float g = acc[i][2 * jp][r];
                float u = acc[i][2 * jp + 1][r];
                float v = g / (1.0f + __expf(-g)) * u * scale;
                Ct[(long long)token * ldct + cb + wn / 2 + jp * 16 + ra] = f2bf(v);
            }
        }
}

// ---------------- Bucket experts from w_route nonzeros + zero H (fused) ----------
// Blocks 0..31: expert e = blockIdx.x. Pass 1: offset = #nonzeros in columns < e,
// cnt = #nonzeros in column e. Pass 2: ordered ballot compaction of token ids.
// Blocks 32..: zero h_bf (16 MB) so unrouted (t,e) entries read as exact 0.
__global__ __launch_bounds__(256) void bucket_zero(const float* __restrict__ wr,
                                                   int* __restrict__ cnt,
                                                   int* __restrict__ toks,
                                                   int4* __restrict__ hz) {
    const int b = blockIdx.x, tid = threadIdx.x;
    if (b >= NEXP) {
        long long i = ((long long)(b - NEXP) * 256 + tid) * 4;
        int4 z = {0, 0, 0, 0};
        hz[i] = z; hz[i + 1] = z; hz[i + 2] = z; hz[i + 3] = z;
        return;
    }
    const int e = b, lane = tid & 63, wv = tid >> 6;
    int myoff = 0, mycnt = 0;
    for (int t = tid; t < TOKENS; t += 256) {
        const float* row = wr + (long long)t * NEXP;
        for (int i = 0; i < e; ++i) myoff += (row[i] != 0.0f);
        mycnt += (row[e] != 0.0f);
    }
    #pragma unroll
    for (int off2 = 32; off2; off2 >>= 1) {
        myoff += __shfl_down(myoff, off2);
        mycnt += __shfl_down(mycnt, off2);
    }
    __shared__ int s_off[4], s_cnt[4];
    __shared__ int base_s;
    __shared__ int wbase[4];
    if (lane == 0) { s_off[wv] = myoff; s_cnt[wv] = mycnt; }
    __syncthreads();
    if (tid == 0) {
        base_s = s_off[0] + s_off[1] + s_off[2] + s_off[3];
        cnt[e] = s_cnt[0] + s_cnt[1] + s_cnt[2] + s_cnt[3];
    }
    __syncthreads();
    for (int t0 = 0; t0 < TOKENS; t0 += 256) {
        int t = t0 + tid;
        bool m = wr[(long long)t * NEXP + e] != 0.0f;
        unsigned long long bl = __ballot(m);
        int wpos = __popcll(bl & ((1ull << lane) - 1ull));
        if (lane == 0) wbase[wv] = __popcll(bl);
        __syncthreads();
        int wb = base_s;
        for (int i = 0; i < wv; ++i) wb += wbase[i];
        if (m) toks[wb + wpos] = t;
        __syncthreads();
        if (tid == 0) base_s += wbase[0] + wbase[1] + wbase[2] + wbase[3];
        __syncthreads();
    }
}

// ---------------- Sparse routed g/u GEMM (gathered rows, gemm_act schedule) ------
// grid MAXTILES. Tile = 64 distinct routed tokens x 256 weight rows of one expert,
// K=1024, dbuf. A rows gathered via per-lane global addrs (async16 src is per-lane).
// Epilogue: silu(g)*u*w_route -> dense h_bf[tok][e*128+col] (pre-zeroed elsewhere).
__global__ __launch_bounds__(256) void gemm_gu(const short* __restrict__ A,
                                               const short* __restrict__ Wgu,
                                               const int* __restrict__ toks,
                                               const int* __restrict__ cnts,
                                               const float* __restrict__ wr,
                                               short* __restrict__ H) {
    __shared__ int ts[NEXP + 1], os[NEXP + 1];
    const int tid = threadIdx.x;
    if (tid == 0) {
        int t = 0, o = 0;
        for (int i = 0; i < NEXP; ++i) {
            ts[i] = t; os[i] = o;
            int c = cnts[i];
            t += (c + 63) >> 6;
            o += c;
        }
        ts[NEXP] = t; os[NEXP] = o;
    }
    __syncthreads();
    const int tile = blockIdx.x;
    if (tile >= ts[NEXP]) return;
    int e = 0;
    while (ts[e + 1] <= tile) ++e;
    const int off = os[e];
    const int cnt = os[e + 1] - off;
    const int m0 = (tile - ts[e]) * 64;
    const int lane = tid & 63, w = tid >> 6;
    __shared__ int tok_s[64];
    __shared__ float gt_s[64];
    if (tid < 64) {
        int lr = m0 + tid;
        int tk = toks[off + (lr < cnt ? lr : 0)];
        tok_s[tid] = tk;
        gt_s[tid] = wr[(long long)tk * NEXP + e];
    }
    __shared__ short As_[2][64 * 64];
    __shared__ short Bs_[2][256 * 64];
    const int wm = (w >> 1) * 32, wn = (w & 1) * 128;
    const int drow = lane >> 3;
    const int dcol = ((lane & 7) ^ drow) * 8;
    __syncthreads();
    const short* ag0 = A + (long long)tok_s[w * 16 + drow] * DIM + dcol;
    const short* ag1 = A + (long long)tok_s[w * 16 + 8 + drow] * DIM + dcol;
    const short* bg  = Wgu + (long long)e * (256 * 1024) + (long long)(w * 64 + drow) * 1024 + dcol;
    f32x4 acc[2][8];
    #pragma unroll
    for (int i = 0; i < 2; ++i)
        #pragma unroll
        for (int j = 0; j < 8; ++j) { f32x4 z = {0.f, 0.f, 0.f, 0.f}; acc[i][j] = z; }
    const int ra = lane & 15, quad = lane >> 4;
    const int fs0 = ((quad + 0) ^ (ra & 7)) * 8;
    const int fs1 = ((quad + 4) ^ (ra & 7)) * 8;
    {
        const short* lA = As_[0] + w * 16 * 64;
        const short* lB = Bs_[0] + w * 64 * 64;
        async16(ag0, lA);
        async16(ag1, lA + 512);
        #pragma unroll
        for (int c = 0; c < 8; ++c)
            async16(bg + (long long)(c * 8) * 1024, lB + c * 512);
    }
    int cur = 0;
    for (int k0 = 0; k0 < 1024; k0 += 64) {
        __syncthreads();
        if (k0 + 64 < 1024) {
            const int nxt = cur ^ 1;
            const short* lA = As_[nxt] + w * 16 * 64;
            const short* lB = Bs_[nxt] + w * 64 * 64;
            async16(ag0 + k0 + 64, lA);
            async16(ag1 + k0 + 64, lA + 512);
            #pragma unroll
            for (int c = 0; c < 8; ++c)
                async16(bg + (long long)(c * 8) * 1024 + k0 + 64, lB + c * 512);
        }
        const short* cA = As_[cur];
        const short* cB = Bs_[cur];
        #pragma unroll
        for (int h = 0; h < 2; ++h) {
            const int fs = h ? fs1 : fs0;
            bf8 af0 = *(const bf8*)(cA + (wm + ra) * 64 + fs);
            bf8 af1 = *(const bf8*)(cA + (wm + 16 + ra) * 64 + fs);
            #pragma unroll
            for (int j = 0; j < 8; ++j) {
                bf8 bv = *(const bf8*)(cB + (wn + j * 16 + ra) * 64 + fs);
                acc[0][j] = __builtin_amdgcn_mfma_f32_16x16x32_bf16(af0, bv, acc[0][j], 0, 0, 0);
                acc[1][j] = __builtin_amdgcn_mfma_f32_16x16x32_bf16(af1, bv, acc[1][j], 0, 0, 0);
            }
        }
        cur ^= 1;
    }
    // epilogue: weight rows wn+j*16+ra; j even = g, j odd = u;
    // h col = e*128 + wn/2 + jp*16 + ra
    #pragma unroll
    for (int i = 0; i < 2; ++i)
        #pragma unroll
        for (int r = 0; r < 4; ++r) {
            int lr = wm + i * 16 + quad * 4 + r;
            bool valid = (m0 + lr) < cnt;
            long long hrow = (long long)tok_s[lr] * (NEXP * EDIM) + e * EDIM;
            float scale = gt_s[lr];
            #pragma unroll
            for (int jp = 0; jp < 4; ++jp) {
                float g = acc[i][2 * jp][r];
                float u = acc[i][2 * jp + 1][r];
                float v = g / (1.0f + __expf(-g)) * u * scale;
                if (valid) H[hrow + wn / 2 + jp * 16 + ra] = f2bf(v);
            }
        }
}

// ---------------- combine: dst = add + sum of 4 fp32 slices ----------------
__global__ void combine4(const float* __restrict__ slices, const float* __restrict__ add,
                         float* __restrict__ dst) {
    long long i = (long long)blockIdx.x * 256 + threadIdx.x;
    const long long S4 = (long long)TOKENS * DIM / 4;
    float4 s = ((const float4*)add)[i];
    #pragma unroll
    for (int c = 0; c < 4; ++c) {
        float4 p = ((const float4*)slices)[c * S4 + i];
        s.x += p.x; s.y += p.y; s.z += p.z; s.w += p.w;
    }
    ((float4*)dst)[i] = s;
}

// ---------------- combine 4 slices + residual -> xffn fp32 AND rmsnorm -> bf16 -------
__global__ __launch_bounds__(256) void combine_rms(const float* __restrict__ slices,
                                                   const float* __restrict__ add,
                                                   const float* __restrict__ w,
                                                   float* __restrict__ xffn,
                                                   short* __restrict__ xf) {
    int row = blockIdx.x, t = threadIdx.x;
    long long i = (long long)row * 256 + t;
    const long long S4 = (long long)TOKENS * DIM / 4;
    float4 s = ((const float4*)add)[i];
    #pragma unroll
    for (int c = 0; c < 4; ++c) {
        float4 p = ((const float4*)slices)[c * S4 + i];
        s.x += p.x; s.y += p.y; s.z += p.z; s.w += p.w;
    }
    ((float4*)xffn)[i] = s;
    float ss = s.x*s.x + s.y*s.y + s.z*s.z + s.w*s.w;
    #pragma unroll
    for (int off = 32; off; off >>= 1) ss += __shfl_down(ss, off);
    __shared__ float warps[4];
    if ((t & 63) == 0) warps[t >> 6] = ss;
    __syncthreads();
    float tot = warps[0] + warps[1] + warps[2] + warps[3];
    float scale = rsqrtf(tot / (float)DIM + EPS_);
    float4 wv = ((const float4*)w)[t];
    short4 o;
    o.x = f2bf(s.x * scale * wv.x);
    o.y = f2bf(s.y * scale * wv.y);
    o.z = f2bf(s.z * scale * wv.z);
    o.w = f2bf(s.w * scale * wv.w);
    ((short4*)(xf + (long long)row * DIM))[t] = o;
}

// ---------------- QKV post (bf16 qkv): split heads, l2norm(q,k), RoPE -> bf16 [h][s][64] ----
__global__ __launch_bounds__(256) void qkv_post(const short* __restrict__ qkv,
                                                short* __restrict__ q,
                                                short* __restrict__ k) {
    int lane = threadIdx.x & 63;
    int sh = blockIdx.x * 4 + (threadIdx.x >> 6);
    int s = sh >> 4;
    int h = sh & 15;
    const short* base = qkv + (long long)s * 3 * DIM;
    float qv = bf2f(base[h * HEADDIM + lane]);
    float kv = bf2f(base[DIM + h * HEADDIM + lane]);
    float qs = qv * qv, ks = kv * kv;
    #pragma unroll
    for (int off = 32; off; off >>= 1) {
        qs += __shfl_xor(qs, off);
        ks += __shfl_xor(ks, off);
    }
    qv /= fmaxf(sqrtf(qs), EPS_);
    kv /= fmaxf(sqrtf(ks), EPS_);
    int i = lane & 31;
    float f = (float)s * powf(10000.0f, -(float)i / 32.0f);
    float c = cosf(f), sn = sinf(f);
    float qo = __shfl_xor(qv, 32);
    float ko = __shfl_xor(kv, 32);
    float sgn = (lane < 32) ? sn : -sn;
    float qr = qv * c + qo * sgn;
    float kr = kv * c + ko * sgn;
    long long o = ((long long)h * TOKENS + s) * HEADDIM + lane;
    q[o] = f2bf(qr);
    k[o] = f2bf(kr);
}

// ---------------- V transpose (bf16 qkv): [s][3D] -> vt bf16 [h][64][2048] ----------------
__global__ __launch_bounds__(256) void vtrans(const short* __restrict__ qkv,
                                              short* __restrict__ vt) {
    int h = blockIdx.z;
    int s0 = blockIdx.x * 32, d0 = blockIdx.y * 32;
    __shared__ short t[32][34];
    int tx = threadIdx.x & 31, ty = threadIdx.x >> 5;
    #pragma unroll
    for (int r = ty; r < 32; r += 8)
        t[r][tx] = qkv[(long long)(s0 + r) * (3 * DIM) + 2 * DIM + h * HEADDIM + d0 + tx];
    __syncthreads();
    #pragma unroll
    for (int r = ty; r < 32; r += 8)
        vt[((long long)h * HEADDIM + d0 + r) * TOKENS + s0 + tx] = t[tx][r];
}

// ---------------- MFMA flash attention: LDS-staged K/V (DMA), key-split combine ----------
#define PLD 68
__global__ __launch_bounds__(256) void attn_kernel(const short* __restrict__ q,
                                                   const short* __restrict__ k,
                                                   const short* __restrict__ vt,
                                                   float* __restrict__ Oacc,
                                                   float* __restrict__ lacc) {
    const int w = threadIdx.x >> 6, lane = threadIdx.x & 63;
    const int col = lane & 15, quad = lane >> 4;
    const int head = blockIdx.x / 80;
    const int t = blockIdx.x % 80;
    int qb, ch;
    if (t < 8)       { qb = t;                ch = 0; }
    else if (t < 24) { qb = 8 + (t - 8) / 2;  ch = (t - 8) % 2; }
    else if (t < 48) { qb = 16 + (t - 24) / 3; ch = (t - 24) % 3; }
    else             { qb = 24 + (t - 48) / 4; ch = (t - 48) % 4; }
    const int nch = qb / 8 + 1;
    const int ntk = qb + 1;
    const int per = (ntk + nch - 1) / nch;
    const int t0 = ch * per;
    const int t1 = (t0 + per < ntk) ? t0 + per : ntk;
    const int qbase = qb * 64 + w * 16;
    __shared__ short Ks[64 * 64];
    __shared__ short Vs[64 * 64];
    __shared__ short Ps[4 * 16 * PLD];
    short* Pw = Ps + w * 16 * PLD;
    const short* kh = k + (long long)head * TOKENS * HEADDIM;
    const short* vh = vt + (long long)head * HEADDIM * TOKENS;
    const int r8 = lane >> 3;
    const int sw = ((lane & 7) ^ r8) * 8;
    bf8 qf[2];
    #pragma unroll
    for (int ks = 0; ks < 2; ++ks)
        qf[ks] = *(const bf8*)(q + ((long long)head * TOKENS + qbase + col) * HEADDIM + ks * 32 + quad * 8);
    const int fo0 = (((0 * 4) + quad) ^ (col & 7)) * 8;
    const int fo1 = (((1 * 4) + quad) ^ (col & 7)) * 8;
    f32x4 o_[4];
    float l_[4];
    #pragma unroll
    for (int n = 0; n < 4; ++n) { f32x4 z = {0.f, 0.f, 0.f, 0.f}; o_[n] = z; }
    #pragma unroll
    for (int r = 0; r < 4; ++r) l_[r] = 0.f;
    for (int kt = t0; kt < t1; ++kt) {
        const int j0 = kt * 64;
        #pragma unroll
        for (int c = 0; c < 2; ++c) {
            int row = w * 16 + c * 8 + r8;
            async16(kh + (long long)(j0 + row) * HEADDIM + sw, Ks + (w * 16 + c * 8) * 64 + lane * 8);
            async16(vh + (long long)row * TOKENS + j0 + sw, Vs + (w * 16 + c * 8) * 64 + lane * 8);
        }
        __syncthreads();
        f32x4 sacc[4];
        #pragma unroll
        for (int n = 0; n < 4; ++n) { f32x4 z = {0.f, 0.f, 0.f, 0.f}; sacc[n] = z; }
        #pragma unroll
        for (int ks = 0; ks < 2; ++ks) {
            const int fo = ks ? fo1 : fo0;
            #pragma unroll
            for (int nt = 0; nt < 4; ++nt) {
                bf8 kf = *(const bf8*)(Ks + (nt * 16 + col) * 64 + fo);
                sacc[nt] = __builtin_amdgcn_mfma_f32_16x16x32_bf16(qf[ks], kf, sacc[nt], 0, 0, 0);
            }
        }
        const bool diag = (j0 + 64 > qbase);
        #pragma unroll
        for (int nt = 0; nt < 4; ++nt)
            #pragma unroll
            for (int r = 0; r < 4; ++r) {
                float p = __expf(sacc[nt][r] * 0.125f);
                if (diag && (j0 + nt * 16 + col > qbase + quad * 4 + r)) p = 0.f;
                l_[r] += p;
                Pw[(quad * 4 + r) * PLD + nt * 16 + col] = f2bf(p);
            }
        #pragma unroll
        for (int ks = 0; ks < 2; ++ks) {
            bf8 pf = *(const bf8*)(Pw + col * PLD + ks * 32 + quad * 8);
            const int fo = ks ? fo1 : fo0;
            #pragma unroll
            for (int nt = 0; nt < 4; ++nt) {
                bf8 vf = *(const bf8*)(Vs + (nt * 16 + col) * 64 + fo);
                o_[nt] = __builtin_amdgcn_mfma_f32_16x16x32_bf16(pf, vf, o_[nt], 0, 0, 0);
            }
        }
        __syncthreads();
    }
    float* Oc = Oacc + (long long)ch * (TOKENS * DIM);
    #pragma unroll
    for (int r = 0; r < 4; ++r) {
        int row = qbase + quad * 4 + r;
        float* op = Oc + (long long)row * DIM + head * HEADDIM;
        #pragma unroll
        for (int nt = 0; nt < 4; ++nt)
            op[nt * 16 + col] = o_[nt][r];
        float l = l_[r];
        #pragma unroll
        for (int off = 1; off < 16; off <<= 1) l += __shfl_xor(l, off);
        if (col == 0) lacc[ch * (TOKENS * NHEADS) + row * NHEADS + head] = l;
    }
}

// ---------------- Attention normalize: xo = sum_ch Oacc / sum_ch l -> bf16 ----------------
__global__ void attn_norm(const float* __restrict__ Oacc, const float* __restrict__ lacc,
                          short* __restrict__ xo) {
    long long i = (long long)blockIdx.x * 256 + threadIdx.x;  // 2M
    int row = (int)(i >> 10), col = (int)(i & 1023);
    int nch = (row >> 9) + 1;
    int head = col >> 6;
    float so = 0.f, sl = 0.f;
    for (int c = 0; c < nch; ++c) {
        so += Oacc[(long long)c * (TOKENS * DIM) + i];
        sl += lacc[c * (TOKENS * NHEADS) + row * NHEADS + head];
    }
    xo[i] = f2bf(so / sl);
}

// ---------------- Router (bf16 x input) -> dense w_route (summed gates) ----------
__global__ __launch_bounds__(256) void router_kernel(const short* __restrict__ xf,
                                                     const float* __restrict__ keys_w,
                                                     const int* __restrict__ idx,
                                                     const float* __restrict__ vals,
                                                     float* __restrict__ w_route) {
    int t = blockIdx.x;
    int tid = threadIdx.x;
    int e = tid & 31, c = tid >> 5;
    const short* xr = xf + (long long)t * DIM;
    float p = 0.f;
    for (int j = 0; j < 128; ++j)
        p += bf2f(xr[c * 128 + j]) * keys_w[(c * 128 + j) * NEXP + e];
    __shared__ float part[8][32];
    part[c][e] = p;
    __syncthreads();
    if (tid < NEXP) {
        float lg = 0.f;
        #pragma unroll
        for (int cc = 0; cc < 8; ++cc) lg += part[cc][tid];
        part[0][tid] = lg;
    }
    __syncthreads();
    __shared__ float gate_s[TOPK];
    __shared__ int idx_s[TOPK];
    if (tid < TOPK) {
        int ii = idx[t * TOPK + tid];
        float g = vals[t * TOPK + tid] + part[0][ii];
        gate_s[tid] = (1.0f / (1.0f + __expf(-g))) * RSF_;
        idx_s[tid] = ii;
    }
    __syncthreads();
    if (tid < NEXP) {
        float wr = 0.f;
        #pragma unroll
        for (int kk = 0; kk < TOPK; ++kk)
            if (idx_s[kk] == tid) wr += gate_s[kk];
        w_route[(long long)t * NEXP + tid] = wr;
    }
}

extern "C" void kernel_launch(void* const* d_in, const int* in_sizes, int n_in,
                              void* d_out, int out_size, void* d_ws, size_t ws_size,
                              hipStream_t stream) {
    (void)in_sizes; (void)n_in; (void)out_size; (void)ws_size;
    const float* x_input     = (const float*)d_in[0];
    const int*   indices     = (const int*)d_in[1];
    const float* values      = (const float*)d_in[2];
    const float* w_attn      = (const float*)d_in[3];
    const float* w_attn_o    = (const float*)d_in[4];
    const float* attn_norm_w = (const float*)d_in[5];
    const float* ffn_norm_w  = (const float*)d_in[6];
    const float* ffn_experts = (const float*)d_in[7];
    const float* keys_w      = (const float*)d_in[8];
    const float* w_up        = (const float*)d_in[9];
    const float* w_down      = (const float*)d_in[10];
    float* out = (float*)d_out;
    float* ws  = (float*)d_ws;

    const long long M1 = 1024 * 1024;
    const long long SLICE = (long long)TOKENS * DIM;  // 2M floats
    // Workspace (float units, lifetime-aliased; max extent 24M floats = 96MB):
    float* xffn    = ws + 0 * M1;                     // [0,2)    whole call
    short* xa_bf   = (short*)(ws + 4 * M1);           // [4,4.5)  phase A only
    short* xf_bf   = (short*)(ws + 4 * M1 + M1 / 2);  // [4.5,5)  until gemm_act<false>
    short* xattn_bf= (short*)(ws + 5 * M1);           // [5,5.5)  phase A only
    float* w_route = ws + 5 * M1 + M1 / 2;            // [5.5,+64K floats)
    int*   cntb    = (int*)(w_route + TOKENS * NEXP); // 32 ints
    int*   toks    = cntb + 32;                       // <=16384 ints
    float* Oacc    = ws + 6 * M1;                     // [6,14)   phase A
    float* lacc    = ws + 14 * M1;                    // [14,14.2) phase A
    short* qh_bf   = (short*)(ws + 15 * M1);          // [15,15.5)
    short* kh_bf   = (short*)(ws + 15 * M1 + M1 / 2); // [15.5,16)
    short* vt_bf   = (short*)(ws + 16 * M1);          // [16,16.5)
    short* wattn_t = (short*)(ws + 17 * M1);          // [17,18.5)
    short* wattno_t= (short*)(ws + 18 * M1 + M1 / 2); // [18.5,19)
    short* qkv_bf  = (short*)(ws + 21 * M1);          // [21,24)  dead after vtrans
    float* oslice  = ws + 6 * M1;                     // [6,14)   dead after combine_rms
    short* wgu     = (short*)(ws + 6 * M1);           // [6,10)   phase B (oslice dead)
    short* h_bf    = (short*)(ws + 10 * M1);          // [10,14)  dense h, zeroed first
    short* w2t     = (short*)(ws + 14 * M1);          // [14,16)  (lacc dead)
    float* yslice  = ws + 16 * M1;                    // [16,24)  (vt/wattn_t/qkv dead)
    short* wupt    = (short*)(ws + 6 * M1);           // [6,8)    phase C (wgu dead)
    short* hs_bf   = (short*)(ws + 8 * M1);           // [8,10)
    short* wdownt  = (short*)(ws + 10 * M1);          // [10,11)  (h_bf dead)

    // ---- phase A: attention ----
    tconv<<<dim3(3072 / 32, DIM / 32, 1), 256, 0, stream>>>(w_attn, 0, wattn_t, 0, DIM, 3 * DIM);
    rmsnorm_kernel<<<TOKENS, 256, 0, stream>>>(x_input, attn_norm_w, xa_bf);
    gemm_bf16<2><<<dim3(3072 / 128, TOKENS / 128, 1), 256, 0, stream>>>(
        xa_bf, DIM, 0, wattn_t, DIM, 0, qkv_bf, 3 * DIM, 0, TOKENS, 3 * DIM, DIM);
    qkv_post<<<(TOKENS * NHEADS) / 4, 256, 0, stream>>>(qkv_bf, qh_bf, kh_bf);
    vtrans<<<dim3(TOKENS / 32, HEADDIM / 32, NHEADS), 256, 0, stream>>>(qkv_bf, vt_bf);
    attn_kernel<<<NHEADS * 80, 256, 0, stream>>>(qh_bf, kh_bf, vt_bf, Oacc, lacc);
    attn_norm<<<(TOKENS * DIM) / 256, 256, 0, stream>>>(Oacc, lacc, xattn_bf);
    tconv<<<dim3(DIM / 32, DIM / 32, 1), 256, 0, stream>>>(w_attn_o, 0, wattno_t, 0, DIM, DIM);
    gemm_bf16<3><<<dim3(DIM / 128, TOKENS / 128, 4), 256, 0, stream>>>(
        xattn_bf, DIM, 0, wattno_t, DIM, 0, oslice, DIM, SLICE, TOKENS, DIM, DIM);
    combine_rms<<<TOKENS, 256, 0, stream>>>(oslice, x_input, ffn_norm_w, xffn, xf_bf);

    // ---- phase B: router + buckets + sparse g/u + dense w2 ----
    router_kernel<<<TOKENS, 256, 0, stream>>>(xf_bf, keys_w, indices, values, w_route);
    bucket_zero<<<NEXP + 1024, 256, 0, stream>>>(w_route, cntb, toks, (int4*)h_bf);
    guconv<<<dim3(EDIM / 32, DIM / 32, 2 * NEXP), 256, 0, stream>>>(ffn_experts, wgu);
    gemm_gu<<<MAXTILES, 256, 0, stream>>>(xf_bf, wgu, toks, cntb, w_route, h_bf);
    w2conv<<<(NEXP * DIM * EDIM) / 256, 256, 0, stream>>>(
        ffn_experts + 2LL * NEXP * DIM * EDIM, w2t);
    gemm_bf16<3><<<dim3(DIM / 128, TOKENS / 128, 4), 256, 0, stream>>>(
        h_bf, NEXP * EDIM, 0, w2t, NEXP * EDIM, 0, yslice, DIM, SLICE, TOKENS, DIM, NEXP * EDIM);

    // ---- phase C: shared expert ----
    upconv<<<dim3((2 * DSHARED) / 32, DIM / 32, 1), 256, 0, stream>>>(w_up, wupt);
    gemm_act<false><<<dim3((2 * DSHARED) / 256, TOKENS / 64, 1), 256, 0, stream>>>(
        xf_bf, DIM, wupt, 0, hs_bf, DSHARED, nullptr);
    tconv<<<dim3(DIM / 32, DSHARED / 32, 1), 256, 0, stream>>>(w_down, 0, wdownt, 0, DSHARED, DIM);
    gemm_bf16<4><<<dim3(DIM / 128, TOKENS / 128, 4), 256, 0, stream>>>(
        hs_bf, DSHARED, 0, wdownt, DSHARED, 0, yslice, DIM, SLICE, TOKENS, DIM, DSHARED);

    // ---- final: out = xffn + sum of 4 slices ----
    combine4<<<(TOKENS * DIM) / 1024, 256, 0, stream>>>(yslice, xffn, out);
}

// Round 6
// 410.486 us; speedup vs baseline: 1.0579x; 1.0579x over previous
//
#include <hip/hip_runtime.h>
#include <math.h>

#define TOKENS 2048
#define DIM 1024
#define NHEADS 16
#define HEADDIM 64
#define NEXP 32
#define EDIM 128
#define TOPK 8
#define DSHARED 2048
#define RSF_ 2.5f
#define EPS_ 1e-6f
#define MAXTILES 288   // sum_e ceil(cnt_e/64) <= 16384/64 + 32

using bf8  = __attribute__((ext_vector_type(8))) short;   // 8 bf16 in 4 VGPRs
using f32x4 = __attribute__((ext_vector_type(4))) float;  // MFMA accumulator

__device__ __forceinline__ short f2bf(float f) {
    unsigned u = __float_as_uint(f);
    unsigned r = (u + 0x7fffu + ((u >> 16) & 1u)) >> 16;
    return (short)r;
}
__device__ __forceinline__ float bf2f(short s) {
    return __uint_as_float(((unsigned)(unsigned short)s) << 16);
}

// Direct global->LDS DMA, 16B per lane. LDS dest = wave-uniform base + lane*16.
// Global source address is PER-LANE -> gathered rows work.
__device__ __forceinline__ void async16(const short* g, const short* l) {
    __builtin_amdgcn_global_load_lds(
        (const __attribute__((address_space(1))) void*)(unsigned long long)g,
        (__attribute__((address_space(3))) void*)(unsigned)(unsigned long long)l,
        16, 0, 0);
}

// ---------------- RMSNorm: one block per token, bf16 output ----------------
__global__ __launch_bounds__(256) void rmsnorm_kernel(const float* __restrict__ x,
                                                      const float* __restrict__ w,
                                                      short* __restrict__ out) {
    int row = blockIdx.x;
    const float* xr = x + (long long)row * DIM;
    int t = threadIdx.x;
    float4 xv = ((const float4*)xr)[t];
    float ss = xv.x*xv.x + xv.y*xv.y + xv.z*xv.z + xv.w*xv.w;
    #pragma unroll
    for (int off = 32; off; off >>= 1) ss += __shfl_down(ss, off);
    __shared__ float warps[4];
    if ((t & 63) == 0) warps[t >> 6] = ss;
    __syncthreads();
    float tot = warps[0] + warps[1] + warps[2] + warps[3];
    float scale = rsqrtf(tot / (float)DIM + EPS_);
    float4 wv = ((const float4*)w)[t];
    short4 o;
    o.x = f2bf(xv.x * scale * wv.x);
    o.y = f2bf(xv.y * scale * wv.y);
    o.z = f2bf(xv.z * scale * wv.z);
    o.w = f2bf(xv.w * scale * wv.w);
    ((short4*)(out + (long long)row * DIM))[t] = o;
}

// ---------------- Transpose + convert: fp32 in[K][N] -> bf16 out[N][K] ----------------
__global__ __launch_bounds__(256) void tconv(const float* __restrict__ in, long long sin,
                                             short* __restrict__ out, long long sout,
                                             int K, int N) {
    in  += (long long)blockIdx.z * sin;
    out += (long long)blockIdx.z * sout;
    __shared__ float t[32][33];
    int n0 = blockIdx.x * 32, k0 = blockIdx.y * 32;
    int tx = threadIdx.x & 31, ty = threadIdx.x >> 5;  // ty 0..7
    #pragma unroll
    for (int r = ty; r < 32; r += 8)
        t[r][tx] = in[(long long)(k0 + r) * N + n0 + tx];
    __syncthreads();
    #pragma unroll
    for (int r = ty; r < 32; r += 8)
        out[(long long)(n0 + r) * K + k0 + tx] = f2bf(t[tx][r]);
}

// W2 [e][d][h] fp32 -> bf16 [d][(e*128+h)]
__global__ void w2conv(const float* __restrict__ in, short* __restrict__ out) {
    long long i = (long long)blockIdx.x * 256 + threadIdx.x;  // 4M
    int e = (int)(i >> 17);
    int d = (int)(i >> 7) & 1023;
    int h = (int)(i & 127);
    out[(long long)d * (NEXP * EDIM) + e * EDIM + h] = f2bf(in[i]);
}

// W0/W1 [e][k=0..1023][c=0..127] fp32 -> wgu'[e] rows rr=(c>>4)*32+half*16+(c&15), col k
__global__ __launch_bounds__(256) void guconv(const float* __restrict__ ex,
                                              short* __restrict__ wgu) {
    int z = blockIdx.z;            // 0..63
    int e = z & 31, hf = z >> 5;
    const float* in = ex + (long long)hf * (NEXP * DIM * EDIM) + (long long)e * (DIM * EDIM);
    short* outp = wgu + (long long)e * (256 * 1024);
    __shared__ float t[32][33];
    int n0 = blockIdx.x * 32, k0 = blockIdx.y * 32;
    int tx = threadIdx.x & 31, ty = threadIdx.x >> 5;
    #pragma unroll
    for (int r = ty; r < 32; r += 8)
        t[r][tx] = in[(long long)(k0 + r) * EDIM + n0 + tx];
    __syncthreads();
    #pragma unroll
    for (int r = ty; r < 32; r += 8) {
        int c = n0 + r;
        int rr = ((c >> 4) << 5) + hf * 16 + (c & 15);
        outp[(long long)rr * 1024 + k0 + tx] = f2bf(t[tx][r]);
    }
}

// w_up [1024][4096] fp32 -> wupt' interleaved rows: for logical col n:
// half=n>>11, c2=n&2047, b=c2>>7, cl=c2&127 -> rr = b*256+(cl>>4)*32+half*16+(cl&15)
__global__ __launch_bounds__(256) void upconv(const float* __restrict__ in,
                                              short* __restrict__ outp) {
    __shared__ float t[32][33];
    int n0 = blockIdx.x * 32, k0 = blockIdx.y * 32;
    int tx = threadIdx.x & 31, ty = threadIdx.x >> 5;
    #pragma unroll
    for (int r = ty; r < 32; r += 8)
        t[r][tx] = in[(long long)(k0 + r) * (2 * DSHARED) + n0 + tx];
    __syncthreads();
    #pragma unroll
    for (int r = ty; r < 32; r += 8) {
        int n = n0 + r;
        int hf = n >> 11, c2 = n & 2047;
        int rr = ((c2 >> 7) << 8) + (((c2 & 127) >> 4) << 5) + hf * 16 + (c2 & 15);
        outp[(long long)rr * 1024 + k0 + tx] = f2bf(t[tx][r]);
    }
}

// ---------------- bf16 MFMA GEMM: C[M][N] = A[M][K] @ Bt[N][K]^T ----------------
// 128x128 tile, BK=64, XOR-swizzled LDS, async global->LDS staging, double-buffered.
// MODE 2: bf16 store, z = batch.
// MODE 3: f32 store, z = K-split slice (sC = slice stride). No atomics.
// MODE 4: f32 read+add+store, z = K-split slice (block-exclusive tiles).
template<int MODE>
__global__ __launch_bounds__(256) void gemm_bf16(const short* __restrict__ A, int lda, long long sA,
                                                 const short* __restrict__ Bt, int ldb, long long sBt,
                                                 void* __restrict__ Cv, int ldc, long long sC,
                                                 int M, int N, int K) {
    int koff = 0, Ksub = K;
    if (MODE >= 3) {
        Ksub = K / gridDim.z;
        koff = blockIdx.z * Ksub;
    } else {
        A  += (long long)blockIdx.z * sA;
        Bt += (long long)blockIdx.z * sBt;
    }
    float* Cf = (float*)Cv;
    short* Cs = (short*)Cv;
    Cf += (long long)blockIdx.z * sC;
    Cs += (long long)blockIdx.z * sC;
    const int m0 = blockIdx.y * 128, n0 = blockIdx.x * 128;
    __shared__ short As[2][128 * 64];
    __shared__ short Bs[2][128 * 64];
    const int tid = threadIdx.x, lane = tid & 63, w = tid >> 6;
    const int wm = (w >> 1) * 64, wn = (w & 1) * 64;
    const int drow = lane >> 3;
    const int dcol = ((lane & 7) ^ drow) * 8;
    const short* ag = A + (long long)(m0 + w * 32 + drow) * lda + koff + dcol;
    const short* bg = Bt + (long long)(n0 + w * 32 + drow) * ldb + koff + dcol;
    f32x4 acc[4][4];
    #pragma unroll
    for (int i = 0; i < 4; ++i)
        #pragma unroll
        for (int j = 0; j < 4; ++j) { f32x4 z = {0.f, 0.f, 0.f, 0.f}; acc[i][j] = z; }
    const int ra = lane & 15, quad = lane >> 4;
    const int fs0 = ((quad + 0) ^ (ra & 7)) * 8;
    const int fs1 = ((quad + 4) ^ (ra & 7)) * 8;
    {
        const short* lA = As[0] + w * 32 * 64;
        const short* lB = Bs[0] + w * 32 * 64;
        #pragma unroll
        for (int c = 0; c < 4; ++c) {
            async16(ag + (long long)(c * 8) * lda, lA + c * 512);
            async16(bg + (long long)(c * 8) * ldb, lB + c * 512);
        }
    }
    int cur = 0;
    for (int k0 = 0; k0 < Ksub; k0 += 64) {
        __syncthreads();
        if (k0 + 64 < Ksub) {
            const int nxt = cur ^ 1;
            const short* lA = As[nxt] + w * 32 * 64;
            const short* lB = Bs[nxt] + w * 32 * 64;
            #pragma unroll
            for (int c = 0; c < 4; ++c) {
                async16(ag + (long long)(c * 8) * lda + k0 + 64, lA + c * 512);
                async16(bg + (long long)(c * 8) * ldb + k0 + 64, lB + c * 512);
            }
        }
        const short* cA = As[cur];
        const short* cB = Bs[cur];
        #pragma unroll
        for (int h = 0; h < 2; ++h) {
            const int fs = h ? fs1 : fs0;
            bf8 af[4], bfv[4];
            #pragma unroll
            for (int i = 0; i < 4; ++i) af[i]  = *(const bf8*)(cA + (wm + i * 16 + ra) * 64 + fs);
            #pragma unroll
            for (int j = 0; j < 4; ++j) bfv[j] = *(const bf8*)(cB + (wn + j * 16 + ra) * 64 + fs);
            #pragma unroll
            for (int i = 0; i < 4; ++i)
                #pragma unroll
                for (int j = 0; j < 4; ++j)
                    acc[i][j] = __builtin_amdgcn_mfma_f32_16x16x32_bf16(af[i], bfv[j], acc[i][j], 0, 0, 0);
        }
        cur ^= 1;
    }
    const int cr = quad * 4, cc = ra;
    #pragma unroll
    for (int i = 0; i < 4; ++i) {
        #pragma unroll
        for (int r = 0; r < 4; ++r) {
            int row = m0 + wm + i * 16 + cr + r;
            long long base = (long long)row * ldc + n0 + wn + cc;
            #pragma unroll
            for (int j = 0; j < 4; ++j) {
                float v = acc[i][j][r];
                if (MODE == 2) Cs[base + j * 16] = f2bf(v);
                if (MODE == 3) Cf[base + j * 16] = v;
                if (MODE == 4) Cf[base + j * 16] = Cf[base + j * 16] + v;
            }
        }
    }
}

// ---------------- Fused GEMM + gated activation (dense; shared-expert up-proj) ----
// Tile: 64 M-rows x 256 weight rows, BK=64, double-buffered (R2-proven).
template<bool SCALED>
__global__ __launch_bounds__(256) void gemm_act(const short* __restrict__ A, int lda,
                                                const short* __restrict__ Bt, long long sBt,
                                                short* __restrict__ Ct, int ldct,
                                                const float* __restrict__ wr) {
    const short* Bp = Bt + (long long)blockIdx.z * sBt + (long long)blockIdx.x * (256 * 1024);
    const int cb = (blockIdx.z * gridDim.x + blockIdx.x) * 128;
    const int m0 = blockIdx.y * 64;
    __shared__ short As[2][64 * 64];
    __shared__ short Bs[2][256 * 64];
    const int tid = threadIdx.x, lane = tid & 63, w = tid >> 6;
    const int wm = (w >> 1) * 32, wn = (w & 1) * 128;
    const int drow = lane >> 3;
    const int dcol = ((lane & 7) ^ drow) * 8;
    const short* ag = A + (long long)(m0 + w * 16 + drow) * lda + dcol;
    const short* bg = Bp + (long long)(w * 64 + drow) * 1024 + dcol;
    f32x4 acc[2][8];
    #pragma unroll
    for (int i = 0; i < 2; ++i)
        #pragma unroll
        for (int j = 0; j < 8; ++j) { f32x4 z = {0.f, 0.f, 0.f, 0.f}; acc[i][j] = z; }
    const int ra = lane & 15, quad = lane >> 4;
    const int fs0 = ((quad + 0) ^ (ra & 7)) * 8;
    const int fs1 = ((quad + 4) ^ (ra & 7)) * 8;
    {
        const short* lA = As[0] + w * 16 * 64;
        const short* lB = Bs[0] + w * 64 * 64;
        async16(ag, lA);
        async16(ag + (long long)8 * lda, lA + 512);
        #pragma unroll
        for (int c = 0; c < 8; ++c)
            async16(bg + (long long)(c * 8) * 1024, lB + c * 512);
    }
    int cur = 0;
    for (int k0 = 0; k0 < 1024; k0 += 64) {
        __syncthreads();
        if (k0 + 64 < 1024) {
            const int nxt = cur ^ 1;
            const short* lA = As[nxt] + w * 16 * 64;
            const short* lB = Bs[nxt] + w * 64 * 64;
            async16(ag + k0 + 64, lA);
            async16(ag + (long long)8 * lda + k0 + 64, lA + 512);
            #pragma unroll
            for (int c = 0; c < 8; ++c)
                async16(bg + (long long)(c * 8) * 1024 + k0 + 64, lB + c * 512);
        }
        const short* cA = As[cur];
        const short* cB = Bs[cur];
        #pragma unroll
        for (int h = 0; h < 2; ++h) {
            const int fs = h ? fs1 : fs0;
            bf8 af0 = *(const bf8*)(cA + (wm + ra) * 64 + fs);
            bf8 af1 = *(const bf8*)(cA + (wm + 16 + ra) * 64 + fs);
            #pragma unroll
            for (int j = 0; j < 8; ++j) {
                bf8 bv = *(const bf8*)(cB + (wn + j * 16 + ra) * 64 + fs);
                acc[0][j] = __builtin_amdgcn_mfma_f32_16x16x32_bf16(af0, bv, acc[0][j], 0, 0, 0);
                acc[1][j] = __builtin_amdgcn_mfma_f32_16x16x32_bf16(af1, bv, acc[1][j], 0, 0, 0);
            }
        }
        cur ^= 1;
    }
    #pragma unroll
    for (int i = 0; i < 2; ++i)
        #pragma unroll
        for (int r = 0; r < 4; ++r) {
            int token = m0 + wm + i * 16 + quad * 4 + r;
            float scale = SCALED ? wr[token * NEXP + blockIdx.z] : 1.0f;
            #pragma unroll
            for (int jp = 0; jp < 4; ++jp) {
                float g = acc[i][2 * jp][r];
                float u = acc[i][2 * jp + 1][r];
                float v = g / (1.0f + __expf(-g)) * u * scale;
                Ct[(long long)token * ldct + cb + wn / 2 + jp * 16 + ra] = f2bf(v);
            }
        }
}

// ---------------- Bucket experts from w_route nonzeros + zero H (fused) ----------
// Blocks 0..31: expert e = blockIdx.x. Pass 1: offset = #nonzeros in columns < e,
// cnt = #nonzeros in column e. Pass 2: ordered ballot compaction of token ids.
// Blocks 32..: zero h_bf (16 MB) so unrouted (t,e) entries read as exact 0.
__global__ __launch_bounds__(256) void bucket_zero(const float* __restrict__ wr,
                                                   int* __restrict__ cnt,
                                                   int* __restrict__ toks,
                                                   int4* __restrict__ hz) {
    const int b = blockIdx.x, tid = threadIdx.x;
    if (b >= NEXP) {
        long long i = ((long long)(b - NEXP) * 256 + tid) * 4;
        int4 z = {0, 0, 0, 0};
        hz[i] = z; hz[i + 1] = z; hz[i + 2] = z; hz[i + 3] = z;
        return;
    }
    const int e = b, lane = tid & 63, wv = tid >> 6;
    int myoff = 0, mycnt = 0;
    for (int t = tid; t < TOKENS; t += 256) {
        const float* row = wr + (long long)t * NEXP;
        for (int i = 0; i < e; ++i) myoff += (row[i] != 0.0f);
        mycnt += (row[e] != 0.0f);
    }
    #pragma unroll
    for (int off2 = 32; off2; off2 >>= 1) {
        myoff += __shfl_down(myoff, off2);
        mycnt += __shfl_down(mycnt, off2);
    }
    __shared__ int s_off[4], s_cnt[4];
    __shared__ int base_s;
    __shared__ int wbase[4];
    if (lane == 0) { s_off[wv] = myoff; s_cnt[wv] = mycnt; }
    __syncthreads();
    if (tid == 0) {
        base_s = s_off[0] + s_off[1] + s_off[2] + s_off[3];
        cnt[e] = s_cnt[0] + s_cnt[1] + s_cnt[2] + s_cnt[3];
    }
    __syncthreads();
    for (int t0 = 0; t0 < TOKENS; t0 += 256) {
        int t = t0 + tid;
        bool m = wr[(long long)t * NEXP + e] != 0.0f;
        unsigned long long bl = __ballot(m);
        int wpos = __popcll(bl & ((1ull << lane) - 1ull));
        if (lane == 0) wbase[wv] = __popcll(bl);
        __syncthreads();
        int wb = base_s;
        for (int i = 0; i < wv; ++i) wb += wbase[i];
        if (m) toks[wb + wpos] = t;
        __syncthreads();
        if (tid == 0) base_s += wbase[0] + wbase[1] + wbase[2] + wbase[3];
        __syncthreads();
    }
}

// ---------------- Sparse routed g/u GEMM v2: N-split + XCD-grouped tiles ---------
// 1-D grid 2*MAXTILES. Decode: xcd = b&7, idx = b>>3, work = xcd*72+idx,
// tile = work>>1, x = work&1 -> each XCD owns a contiguous range of 36 tiles, so
// an expert's B half-panel is fetched into <=2 XCD L2s instead of 8.
// Tile = 64 gathered tokens x 128 weight rows (half-panel x of this tile's
// expert), K=1024, dbuf. 576 blocks = 2.25/CU co-residency (latency hiding).
// Epilogue: silu(g)*u*w_route -> dense h_bf[tok][e*128 + x*64 + col].
__global__ __launch_bounds__(256) void gemm_gu(const short* __restrict__ A,
                                               const short* __restrict__ Wgu,
                                               const int* __restrict__ toks,
                                               const int* __restrict__ cnts,
                                               const float* __restrict__ wr,
                                               short* __restrict__ H) {
    __shared__ int ts[NEXP + 1], os[NEXP + 1];
    const int tid = threadIdx.x;
    if (tid == 0) {
        int t = 0, o = 0;
        for (int i = 0; i < NEXP; ++i) {
            ts[i] = t; os[i] = o;
            int c = cnts[i];
            t += (c + 63) >> 6;
            o += c;
        }
        ts[NEXP] = t; os[NEXP] = o;
    }
    __syncthreads();
    const int b = blockIdx.x;                 // 0..575
    const int work = (b & 7) * (MAXTILES / 4) + (b >> 3);  // xcd*72 + idx
    const int tile = work >> 1, x = work & 1;
    if (tile >= ts[NEXP]) return;
    int e = 0;
    while (ts[e + 1] <= tile) ++e;
    const int off = os[e];
    const int cnt = os[e + 1] - off;
    const int m0 = (tile - ts[e]) * 64;
    const int lane = tid & 63, w = tid >> 6;
    __shared__ int tok_s[64];
    __shared__ float gt_s[64];
    if (tid < 64) {
        int lr = m0 + tid;
        int tk = toks[off + (lr < cnt ? lr : 0)];
        tok_s[tid] = tk;
        gt_s[tid] = wr[(long long)tk * NEXP + e];
    }
    __shared__ short As_[2][64 * 64];
    __shared__ short Bs_[2][128 * 64];
    const int wm = (w >> 1) * 32, wn = (w & 1) * 64;
    const int drow = lane >> 3;
    const int dcol = ((lane & 7) ^ drow) * 8;
    __syncthreads();
    const short* ag0 = A + (long long)tok_s[w * 16 + drow] * DIM + dcol;
    const short* ag1 = A + (long long)tok_s[w * 16 + 8 + drow] * DIM + dcol;
    const short* bg  = Wgu + (long long)e * (256 * 1024)
                     + (long long)(x * 128 + w * 32 + drow) * 1024 + dcol;
    f32x4 acc[2][4];
    #pragma unroll
    for (int i = 0; i < 2; ++i)
        #pragma unroll
        for (int j = 0; j < 4; ++j) { f32x4 z = {0.f, 0.f, 0.f, 0.f}; acc[i][j] = z; }
    const int ra = lane & 15, quad = lane >> 4;
    const int fs0 = ((quad + 0) ^ (ra & 7)) * 8;
    const int fs1 = ((quad + 4) ^ (ra & 7)) * 8;
    {
        const short* lA = As_[0] + w * 16 * 64;
        const short* lB = Bs_[0] + w * 32 * 64;
        async16(ag0, lA);
        async16(ag1, lA + 512);
        #pragma unroll
        for (int c = 0; c < 4; ++c)
            async16(bg + (long long)(c * 8) * 1024, lB + c * 512);
    }
    int cur = 0;
    for (int k0 = 0; k0 < 1024; k0 += 64) {
        __syncthreads();
        if (k0 + 64 < 1024) {
            const int nxt = cur ^ 1;
            const short* lA = As_[nxt] + w * 16 * 64;
            const short* lB = Bs_[nxt] + w * 32 * 64;
            async16(ag0 + k0 + 64, lA);
            async16(ag1 + k0 + 64, lA + 512);
            #pragma unroll
            for (int c = 0; c < 4; ++c)
                async16(bg + (long long)(c * 8) * 1024 + k0 + 64, lB + c * 512);
        }
        const short* cA = As_[cur];
        const short* cB = Bs_[cur];
        #pragma unroll
        for (int h = 0; h < 2; ++h) {
            const int fs = h ? fs1 : fs0;
            bf8 af[2], bfv[4];
            #pragma unroll
            for (int i = 0; i < 2; ++i) af[i] = *(const bf8*)(cA + (wm + i * 16 + ra) * 64 + fs);
            #pragma unroll
            for (int j = 0; j < 4; ++j) bfv[j] = *(const bf8*)(cB + (wn + j * 16 + ra) * 64 + fs);
            #pragma unroll
            for (int i = 0; i < 2; ++i)
                #pragma unroll
                for (int j = 0; j < 4; ++j)
                    acc[i][j] = __builtin_amdgcn_mfma_f32_16x16x32_bf16(af[i], bfv[j], acc[i][j], 0, 0, 0);
        }
        cur ^= 1;
    }
    // epilogue: global weight row rr = x*128 + wn + j*16 + ra; pair (j even=g, j odd=u);
    // h col = e*128 + x*64 + wn/2 + jp*16 + ra
    #pragma unroll
    for (int i = 0; i < 2; ++i)
        #pragma unroll
        for (int r = 0; r < 4; ++r) {
            int lr = wm + i * 16 + quad * 4 + r;
            bool valid = (m0 + lr) < cnt;
            long long hrow = (long long)tok_s[lr] * (NEXP * EDIM) + e * EDIM + x * 64;
            float scale = gt_s[lr];
            #pragma unroll
            for (int jp = 0; jp < 2; ++jp) {
                float g = acc[i][2 * jp][r];
                float u = acc[i][2 * jp + 1][r];
                float v = g / (1.0f + __expf(-g)) * u * scale;
                if (valid) H[hrow + wn / 2 + jp * 16 + ra] = f2bf(v);
            }
        }
}

// ---------------- combine: dst = add + sum of 4 fp32 slices ----------------
__global__ void combine4(const float* __restrict__ slices, const float* __restrict__ add,
                         float* __restrict__ dst) {
    long long i = (long long)blockIdx.x * 256 + threadIdx.x;
    const long long S4 = (long long)TOKENS * DIM / 4;
    float4 s = ((const float4*)add)[i];
    #pragma unroll
    for (int c = 0; c < 4; ++c) {
        float4 p = ((const float4*)slices)[c * S4 + i];
        s.x += p.x; s.y += p.y; s.z += p.z; s.w += p.w;
    }
    ((float4*)dst)[i] = s;
}

// ---------------- combine 4 slices + residual -> xffn fp32 AND rmsnorm -> bf16 -------
__global__ __launch_bounds__(256) void combine_rms(const float* __restrict__ slices,
                                                   const float* __restrict__ add,
                                                   const float* __restrict__ w,
                                                   float* __restrict__ xffn,
                                                   short* __restrict__ xf) {
    int row = blockIdx.x, t = threadIdx.x;
    long long i = (long long)row * 256 + t;
    const long long S4 = (long long)TOKENS * DIM / 4;
    float4 s = ((const float4*)add)[i];
    #pragma unroll
    for (int c = 0; c < 4; ++c) {
        float4 p = ((const float4*)slices)[c * S4 + i];
        s.x += p.x; s.y += p.y; s.z += p.z; s.w += p.w;
    }
    ((float4*)xffn)[i] = s;
    float ss = s.x*s.x + s.y*s.y + s.z*s.z + s.w*s.w;
    #pragma unroll
    for (int off = 32; off; off >>= 1) ss += __shfl_down(ss, off);
    __shared__ float warps[4];
    if ((t & 63) == 0) warps[t >> 6] = ss;
    __syncthreads();
    float tot = warps[0] + warps[1] + warps[2] + warps[3];
    float scale = rsqrtf(tot / (float)DIM + EPS_);
    float4 wv = ((const float4*)w)[t];
    short4 o;
    o.x = f2bf(s.x * scale * wv.x);
    o.y = f2bf(s.y * scale * wv.y);
    o.z = f2bf(s.z * scale * wv.z);
    o.w = f2bf(s.w * scale * wv.w);
    ((short4*)(xf + (long long)row * DIM))[t] = o;
}

// ---------------- QKV post (bf16 qkv): split heads, l2norm(q,k), RoPE -> bf16 [h][s][64] ----
__global__ __launch_bounds__(256) void qkv_post(const short* __restrict__ qkv,
                                                short* __restrict__ q,
                                                short* __restrict__ k) {
    int lane = threadIdx.x & 63;
    int sh = blockIdx.x * 4 + (threadIdx.x >> 6);
    int s = sh >> 4;
    int h = sh & 15;
    const short* base = qkv + (long long)s * 3 * DIM;
    float qv = bf2f(base[h * HEADDIM + lane]);
    float kv = bf2f(base[DIM + h * HEADDIM + lane]);
    float qs = qv * qv, ks = kv * kv;
    #pragma unroll
    for (int off = 32; off; off >>= 1) {
        qs += __shfl_xor(qs, off);
        ks += __shfl_xor(ks, off);
    }
    qv /= fmaxf(sqrtf(qs), EPS_);
    kv /= fmaxf(sqrtf(ks), EPS_);
    int i = lane & 31;
    float f = (float)s * powf(10000.0f, -(float)i / 32.0f);
    float c = cosf(f), sn = sinf(f);
    float qo = __shfl_xor(qv, 32);
    float ko = __shfl_xor(kv, 32);
    float sgn = (lane < 32) ? sn : -sn;
    float qr = qv * c + qo * sgn;
    float kr = kv * c + ko * sgn;
    long long o = ((long long)h * TOKENS + s) * HEADDIM + lane;
    q[o] = f2bf(qr);
    k[o] = f2bf(kr);
}

// ---------------- V transpose (bf16 qkv): [s][3D] -> vt bf16 [h][64][2048] ----------------
__global__ __launch_bounds__(256) void vtrans(const short* __restrict__ qkv,
                                              short* __restrict__ vt) {
    int h = blockIdx.z;
    int s0 = blockIdx.x * 32, d0 = blockIdx.y * 32;
    __shared__ short t[32][34];
    int tx = threadIdx.x & 31, ty = threadIdx.x >> 5;
    #pragma unroll
    for (int r = ty; r < 32; r += 8)
        t[r][tx] = qkv[(long long)(s0 + r) * (3 * DIM) + 2 * DIM + h * HEADDIM + d0 + tx];
    __syncthreads();
    #pragma unroll
    for (int r = ty; r < 32; r += 8)
        vt[((long long)h * HEADDIM + d0 + r) * TOKENS + s0 + tx] = t[tx][r];
}

// ---------------- MFMA flash attention: LDS-staged K/V (DMA), key-split combine ----------
#define PLD 68
__global__ __launch_bounds__(256) void attn_kernel(const short* __restrict__ q,
                                                   const short* __restrict__ k,
                                                   const short* __restrict__ vt,
                                                   float* __restrict__ Oacc,
                                                   float* __restrict__ lacc) {
    const int w = threadIdx.x >> 6, lane = threadIdx.x & 63;
    const int col = lane & 15, quad = lane >> 4;
    const int head = blockIdx.x / 80;
    const int t = blockIdx.x % 80;
    int qb, ch;
    if (t < 8)       { qb = t;                ch = 0; }
    else if (t < 24) { qb = 8 + (t - 8) / 2;  ch = (t - 8) % 2; }
    else if (t < 48) { qb = 16 + (t - 24) / 3; ch = (t - 24) % 3; }
    else             { qb = 24 + (t - 48) / 4; ch = (t - 48) % 4; }
    const int nch = qb / 8 + 1;
    const int ntk = qb + 1;
    const int per = (ntk + nch - 1) / nch;
    const int t0 = ch * per;
    const int t1 = (t0 + per < ntk) ? t0 + per : ntk;
    const int qbase = qb * 64 + w * 16;
    __shared__ short Ks[64 * 64];
    __shared__ short Vs[64 * 64];
    __shared__ short Ps[4 * 16 * PLD];
    short* Pw = Ps + w * 16 * PLD;
    const short* kh = k + (long long)head * TOKENS * HEADDIM;
    const short* vh = vt + (long long)head * HEADDIM * TOKENS;
    const int r8 = lane >> 3;
    const int sw = ((lane & 7) ^ r8) * 8;
    bf8 qf[2];
    #pragma unroll
    for (int ks = 0; ks < 2; ++ks)
        qf[ks] = *(const bf8*)(q + ((long long)head * TOKENS + qbase + col) * HEADDIM + ks * 32 + quad * 8);
    const int fo0 = (((0 * 4) + quad) ^ (col & 7)) * 8;
    const int fo1 = (((1 * 4) + quad) ^ (col & 7)) * 8;
    f32x4 o_[4];
    float l_[4];
    #pragma unroll
    for (int n = 0; n < 4; ++n) { f32x4 z = {0.f, 0.f, 0.f, 0.f}; o_[n] = z; }
    #pragma unroll
    for (int r = 0; r < 4; ++r) l_[r] = 0.f;
    for (int kt = t0; kt < t1; ++kt) {
        const int j0 = kt * 64;
        #pragma unroll
        for (int c = 0; c < 2; ++c) {
            int row = w * 16 + c * 8 + r8;
            async16(kh + (long long)(j0 + row) * HEADDIM + sw, Ks + (w * 16 + c * 8) * 64 + lane * 8);
            async16(vh + (long long)row * TOKENS + j0 + sw, Vs + (w * 16 + c * 8) * 64 + lane * 8);
        }
        __syncthreads();
        f32x4 sacc[4];
        #pragma unroll
        for (int n = 0; n < 4; ++n) { f32x4 z = {0.f, 0.f, 0.f, 0.f}; sacc[n] = z; }
        #pragma unroll
        for (int ks = 0; ks < 2; ++ks) {
            const int fo = ks ? fo1 : fo0;
            #pragma unroll
            for (int nt = 0; nt < 4; ++nt) {
                bf8 kf = *(const bf8*)(Ks + (nt * 16 + col) * 64 + fo);
                sacc[nt] = __builtin_amdgcn_mfma_f32_16x16x32_bf16(qf[ks], kf, sacc[nt], 0, 0, 0);
            }
        }
        const bool diag = (j0 + 64 > qbase);
        #pragma unroll
        for (int nt = 0; nt < 4; ++nt)
            #pragma unroll
            for (int r = 0; r < 4; ++r) {
                float p = __expf(sacc[nt][r] * 0.125f);
                if (diag && (j0 + nt * 16 + col > qbase + quad * 4 + r)) p = 0.f;
                l_[r] += p;
                Pw[(quad * 4 + r) * PLD + nt * 16 + col] = f2bf(p);
            }
        #pragma unroll
        for (int ks = 0; ks < 2; ++ks) {
            bf8 pf = *(const bf8*)(Pw + col * PLD + ks * 32 + quad * 8);
            const int fo = ks ? fo1 : fo0;
            #pragma unroll
            for (int nt = 0; nt < 4; ++nt) {
                bf8 vf = *(const bf8*)(Vs + (nt * 16 + col) * 64 + fo);
                o_[nt] = __builtin_amdgcn_mfma_f32_16x16x32_bf16(pf, vf, o_[nt], 0, 0, 0);
            }
        }
        __syncthreads();
    }
    float* Oc = Oacc + (long long)ch * (TOKENS * DIM);
    #pragma unroll
    for (int r = 0; r < 4; ++r) {
        int row = qbase + quad * 4 + r;
        float* op = Oc + (long long)row * DIM + head * HEADDIM;
        #pragma unroll
        for (int nt = 0; nt < 4; ++nt)
            op[nt * 16 + col] = o_[nt][r];
        float l = l_[r];
        #pragma unroll
        for (int off = 1; off < 16; off <<= 1) l += __shfl_xor(l, off);
        if (col == 0) lacc[ch * (TOKENS * NHEADS) + row * NHEADS + head] = l;
    }
}

// ---------------- Attention normalize: xo = sum_ch Oacc / sum_ch l -> bf16 ----------------
__global__ void attn_norm(const float* __restrict__ Oacc, const float* __restrict__ lacc,
                          short* __restrict__ xo) {
    long long i = (long long)blockIdx.x * 256 + threadIdx.x;  // 2M
    int row = (int)(i >> 10), col = (int)(i & 1023);
    int nch = (row >> 9) + 1;
    int head = col >> 6;
    float so = 0.f, sl = 0.f;
    for (int c = 0; c < nch; ++c) {
        so += Oacc[(long long)c * (TOKENS * DIM) + i];
        sl += lacc[c * (TOKENS * NHEADS) + row * NHEADS + head];
    }
    xo[i] = f2bf(so / sl);
}

// ---------------- Router (bf16 x input) -> dense w_route (summed gates) ----------
__global__ __launch_bounds__(256) void router_kernel(const short* __restrict__ xf,
                                                     const float* __restrict__ keys_w,
                                                     const int* __restrict__ idx,
                                                     const float* __restrict__ vals,
                                                     float* __restrict__ w_route) {
    int t = blockIdx.x;
    int tid = threadIdx.x;
    int e = tid & 31, c = tid >> 5;
    const short* xr = xf + (long long)t * DIM;
    float p = 0.f;
    for (int j = 0; j < 128; ++j)
        p += bf2f(xr[c * 128 + j]) * keys_w[(c * 128 + j) * NEXP + e];
    __shared__ float part[8][32];
    part[c][e] = p;
    __syncthreads();
    if (tid < NEXP) {
        float lg = 0.f;
        #pragma unroll
        for (int cc = 0; cc < 8; ++cc) lg += part[cc][tid];
        part[0][tid] = lg;
    }
    __syncthreads();
    __shared__ float gate_s[TOPK];
    __shared__ int idx_s[TOPK];
    if (tid < TOPK) {
        int ii = idx[t * TOPK + tid];
        float g = vals[t * TOPK + tid] + part[0][ii];
        gate_s[tid] = (1.0f / (1.0f + __expf(-g))) * RSF_;
        idx_s[tid] = ii;
    }
    __syncthreads();
    if (tid < NEXP) {
        float wr = 0.f;
        #pragma unroll
        for (int kk = 0; kk < TOPK; ++kk)
            if (idx_s[kk] == tid) wr += gate_s[kk];
        w_route[(long long)t * NEXP + tid] = wr;
    }
}

extern "C" void kernel_launch(void* const* d_in, const int* in_sizes, int n_in,
                              void* d_out, int out_size, void* d_ws, size_t ws_size,
                              hipStream_t stream) {
    (void)in_sizes; (void)n_in; (void)out_size; (void)ws_size;
    const float* x_input     = (const float*)d_in[0];
    const int*   indices     = (const int*)d_in[1];
    const float* values      = (const float*)d_in[2];
    const float* w_attn      = (const float*)d_in[3];
    const float* w_attn_o    = (const float*)d_in[4];
    const float* attn_norm_w = (const float*)d_in[5];
    const float* ffn_norm_w  = (const float*)d_in[6];
    const float* ffn_experts = (const float*)d_in[7];
    const float* keys_w      = (const float*)d_in[8];
    const float* w_up        = (const float*)d_in[9];
    const float* w_down      = (const float*)d_in[10];
    float* out = (float*)d_out;
    float* ws  = (float*)d_ws;

    const long long M1 = 1024 * 1024;
    const long long SLICE = (long long)TOKENS * DIM;  // 2M floats
    // Workspace (float units, lifetime-aliased; max extent 24M floats = 96MB):
    float* xffn    = ws + 0 * M1;                     // [0,2)    whole call
    short* xa_bf   = (short*)(ws + 4 * M1);           // [4,4.5)  phase A only
    short* xf_bf   = (short*)(ws + 4 * M1 + M1 / 2);  // [4.5,5)  until gemm_act<false>
    short* xattn_bf= (short*)(ws + 5 * M1);           // [5,5.5)  phase A only
    float* w_route = ws + 5 * M1 + M1 / 2;            // [5.5,+64K floats)
    int*   cntb    = (int*)(w_route + TOKENS * NEXP); // 32 ints
    int*   toks    = cntb + 32;                       // <=16384 ints
    float* Oacc    = ws + 6 * M1;                     // [6,14)   phase A
    float* lacc    = ws + 14 * M1;                    // [14,14.2) phase A
    short* qh_bf   = (short*)(ws + 15 * M1);          // [15,15.5)
    short* kh_bf   = (short*)(ws + 15 * M1 + M1 / 2); // [15.5,16)
    short* vt_bf   = (short*)(ws + 16 * M1);          // [16,16.5)
    short* wattn_t = (short*)(ws + 17 * M1);          // [17,18.5)
    short* wattno_t= (short*)(ws + 18 * M1 + M1 / 2); // [18.5,19)
    short* qkv_bf  = (short*)(ws + 21 * M1);          // [21,24)  dead after vtrans
    float* oslice  = ws + 6 * M1;                     // [6,14)   dead after combine_rms
    short* wgu     = (short*)(ws + 6 * M1);           // [6,10)   phase B (oslice dead)
    short* h_bf    = (short*)(ws + 10 * M1);          // [10,14)  dense h, zeroed first
    short* w2t     = (short*)(ws + 14 * M1);          // [14,16)  (lacc dead)
    float* yslice  = ws + 16 * M1;                    // [16,24)  (vt/wattn_t/qkv dead)
    short* wupt    = (short*)(ws + 6 * M1);           // [6,8)    phase C (wgu dead)
    short* hs_bf   = (short*)(ws + 8 * M1);           // [8,10)
    short* wdownt  = (short*)(ws + 10 * M1);          // [10,11)  (h_bf dead)

    // ---- phase A: attention ----
    tconv<<<dim3(3072 / 32, DIM / 32, 1), 256, 0, stream>>>(w_attn, 0, wattn_t, 0, DIM, 3 * DIM);
    rmsnorm_kernel<<<TOKENS, 256, 0, stream>>>(x_input, attn_norm_w, xa_bf);
    gemm_bf16<2><<<dim3(3072 / 128, TOKENS / 128, 1), 256, 0, stream>>>(
        xa_bf, DIM, 0, wattn_t, DIM, 0, qkv_bf, 3 * DIM, 0, TOKENS, 3 * DIM, DIM);
    qkv_post<<<(TOKENS * NHEADS) / 4, 256, 0, stream>>>(qkv_bf, qh_bf, kh_bf);
    vtrans<<<dim3(TOKENS / 32, HEADDIM / 32, NHEADS), 256, 0, stream>>>(qkv_bf, vt_bf);
    attn_kernel<<<NHEADS * 80, 256, 0, stream>>>(qh_bf, kh_bf, vt_bf, Oacc, lacc);
    attn_norm<<<(TOKENS * DIM) / 256, 256, 0, stream>>>(Oacc, lacc, xattn_bf);
    tconv<<<dim3(DIM / 32, DIM / 32, 1), 256, 0, stream>>>(w_attn_o, 0, wattno_t, 0, DIM, DIM);
    gemm_bf16<3><<<dim3(DIM / 128, TOKENS / 128, 4), 256, 0, stream>>>(
        xattn_bf, DIM, 0, wattno_t, DIM, 0, oslice, DIM, SLICE, TOKENS, DIM, DIM);
    combine_rms<<<TOKENS, 256, 0, stream>>>(oslice, x_input, ffn_norm_w, xffn, xf_bf);

    // ---- phase B: router + buckets + sparse g/u + dense w2 ----
    router_kernel<<<TOKENS, 256, 0, stream>>>(xf_bf, keys_w, indices, values, w_route);
    bucket_zero<<<NEXP + 1024, 256, 0, stream>>>(w_route, cntb, toks, (int4*)h_bf);
    guconv<<<dim3(EDIM / 32, DIM / 32, 2 * NEXP), 256, 0, stream>>>(ffn_experts, wgu);
    gemm_gu<<<2 * MAXTILES, 256, 0, stream>>>(xf_bf, wgu, toks, cntb, w_route, h_bf);
    w2conv<<<(NEXP * DIM * EDIM) / 256, 256, 0, stream>>>(
        ffn_experts + 2LL * NEXP * DIM * EDIM, w2t);
    gemm_bf16<3><<<dim3(DIM / 128, TOKENS / 128, 4), 256, 0, stream>>>(
        h_bf, NEXP * EDIM, 0, w2t, NEXP * EDIM, 0, yslice, DIM, SLICE, TOKENS, DIM, NEXP * EDIM);

    // ---- phase C: shared expert ----
    upconv<<<dim3((2 * DSHARED) / 32, DIM / 32, 1), 256, 0, stream>>>(w_up, wupt);
    gemm_act<false><<<dim3((2 * DSHARED) / 256, TOKENS / 64, 1), 256, 0, stream>>>(
        xf_bf, DIM, wupt, 0, hs_bf, DSHARED, nullptr);
    tconv<<<dim3(DIM / 32, DSHARED / 32, 1), 256, 0, stream>>>(w_down, 0, wdownt, 0, DSHARED, DIM);
    gemm_bf16<4><<<dim3(DIM / 128, TOKENS / 128, 4), 256, 0, stream>>>(
        hs_bf, DSHARED, 0, wdownt, DSHARED, 0, yslice, DIM, SLICE, TOKENS, DIM, DSHARED);

    // ---- final: out = xffn + sum of 4 slices ----
    combine4<<<(TOKENS * DIM) / 1024, 256, 0, stream>>>(yslice, xffn, out);
}

// Round 9
// 407.416 us; speedup vs baseline: 1.0659x; 1.0075x over previous
//
#include <hip/hip_runtime.h>
#include <math.h>

#define TOKENS 2048
#define DIM 1024
#define NHEADS 16
#define HEADDIM 64
#define NEXP 32
#define EDIM 128
#define TOPK 8
#define DSHARED 2048
#define RSF_ 2.5f
#define EPS_ 1e-6f

using bf8  = __attribute__((ext_vector_type(8))) short;   // 8 bf16 in 4 VGPRs
using f32x4 = __attribute__((ext_vector_type(4))) float;  // MFMA accumulator

__device__ __forceinline__ short f2bf(float f) {
    unsigned u = __float_as_uint(f);
    unsigned r = (u + 0x7fffu + ((u >> 16) & 1u)) >> 16;
    return (short)r;
}
__device__ __forceinline__ float bf2f(short s) {
    return __uint_as_float(((unsigned)(unsigned short)s) << 16);
}

// Direct global->LDS DMA, 16B per lane. LDS dest = wave-uniform base + lane*16.
__device__ __forceinline__ void async16(const short* g, const short* l) {
    __builtin_amdgcn_global_load_lds(
        (const __attribute__((address_space(1))) void*)(unsigned long long)g,
        (__attribute__((address_space(3))) void*)(unsigned)(unsigned long long)l,
        16, 0, 0);
}

// ---------------- RMSNorm: one block per token, bf16 output ----------------
__global__ __launch_bounds__(256) void rmsnorm_kernel(const float* __restrict__ x,
                                                      const float* __restrict__ w,
                                                      short* __restrict__ out) {
    int row = blockIdx.x;
    const float* xr = x + (long long)row * DIM;
    int t = threadIdx.x;
    float4 xv = ((const float4*)xr)[t];
    float ss = xv.x*xv.x + xv.y*xv.y + xv.z*xv.z + xv.w*xv.w;
    #pragma unroll
    for (int off = 32; off; off >>= 1) ss += __shfl_down(ss, off);
    __shared__ float warps[4];
    if ((t & 63) == 0) warps[t >> 6] = ss;
    __syncthreads();
    float tot = warps[0] + warps[1] + warps[2] + warps[3];
    float scale = rsqrtf(tot / (float)DIM + EPS_);
    float4 wv = ((const float4*)w)[t];
    short4 o;
    o.x = f2bf(xv.x * scale * wv.x);
    o.y = f2bf(xv.y * scale * wv.y);
    o.z = f2bf(xv.z * scale * wv.z);
    o.w = f2bf(xv.w * scale * wv.w);
    ((short4*)(out + (long long)row * DIM))[t] = o;
}

// ---------------- Transpose + convert: fp32 in[K][N] -> bf16 out[N][K] ----------------
__global__ __launch_bounds__(256) void tconv(const float* __restrict__ in, long long sin,
                                             short* __restrict__ out, long long sout,
                                             int K, int N) {
    in  += (long long)blockIdx.z * sin;
    out += (long long)blockIdx.z * sout;
    __shared__ float t[32][33];
    int n0 = blockIdx.x * 32, k0 = blockIdx.y * 32;
    int tx = threadIdx.x & 31, ty = threadIdx.x >> 5;  // ty 0..7
    #pragma unroll
    for (int r = ty; r < 32; r += 8)
        t[r][tx] = in[(long long)(k0 + r) * N + n0 + tx];
    __syncthreads();
    #pragma unroll
    for (int r = ty; r < 32; r += 8)
        out[(long long)(n0 + r) * K + k0 + tx] = f2bf(t[tx][r]);
}

// W2 [e][d][h] fp32 -> bf16 [d][(e*128+h)]
__global__ void w2conv(const float* __restrict__ in, short* __restrict__ out) {
    long long i = (long long)blockIdx.x * 256 + threadIdx.x;  // 4M
    int e = (int)(i >> 17);
    int d = (int)(i >> 7) & 1023;
    int h = (int)(i & 127);
    out[(long long)d * (NEXP * EDIM) + e * EDIM + h] = f2bf(in[i]);
}

// W0/W1 [e][k=0..1023][c=0..127] fp32 -> wgu'[e] rows rr=(c>>4)*32+half*16+(c&15), col k
__global__ __launch_bounds__(256) void guconv(const float* __restrict__ ex,
                                              short* __restrict__ wgu) {
    int z = blockIdx.z;            // 0..63
    int e = z & 31, hf = z >> 5;
    const float* in = ex + (long long)hf * (NEXP * DIM * EDIM) + (long long)e * (DIM * EDIM);
    short* outp = wgu + (long long)e * (256 * 1024);
    __shared__ float t[32][33];
    int n0 = blockIdx.x * 32, k0 = blockIdx.y * 32;
    int tx = threadIdx.x & 31, ty = threadIdx.x >> 5;
    #pragma unroll
    for (int r = ty; r < 32; r += 8)
        t[r][tx] = in[(long long)(k0 + r) * EDIM + n0 + tx];
    __syncthreads();
    #pragma unroll
    for (int r = ty; r < 32; r += 8) {
        int c = n0 + r;
        int rr = ((c >> 4) << 5) + hf * 16 + (c & 15);
        outp[(long long)rr * 1024 + k0 + tx] = f2bf(t[tx][r]);
    }
}

// w_up [1024][4096] fp32 -> wupt' interleaved rows: for logical col n:
// half=n>>11, c2=n&2047, b=c2>>7, cl=c2&127 -> rr = b*256+(cl>>4)*32+half*16+(cl&15)
__global__ __launch_bounds__(256) void upconv(const float* __restrict__ in,
                                              short* __restrict__ outp) {
    __shared__ float t[32][33];
    int n0 = blockIdx.x * 32, k0 = blockIdx.y * 32;
    int tx = threadIdx.x & 31, ty = threadIdx.x >> 5;
    #pragma unroll
    for (int r = ty; r < 32; r += 8)
        t[r][tx] = in[(long long)(k0 + r) * (2 * DSHARED) + n0 + tx];
    __syncthreads();
    #pragma unroll
    for (int r = ty; r < 32; r += 8) {
        int n = n0 + r;
        int hf = n >> 11, c2 = n & 2047;
        int rr = ((c2 >> 7) << 8) + (((c2 & 127) >> 4) << 5) + hf * 16 + (c2 & 15);
        outp[(long long)rr * 1024 + k0 + tx] = f2bf(t[tx][r]);
    }
}

// ---------------- bf16 MFMA GEMM: C[M][N] = A[M][K] @ Bt[N][K]^T ----------------
// 128x128 tile, BK=64, XOR-swizzled LDS, async global->LDS staging, double-buffered.
// MODE 2: bf16 store, z = batch.
// MODE 3: f32 store, z = K-split slice (sC = slice stride). No atomics.
// MODE 4: f32 read+add+store, z = K-split slice (block-exclusive tiles).
template<int MODE>
__global__ __launch_bounds__(256) void gemm_bf16(const short* __restrict__ A, int lda, long long sA,
                                                 const short* __restrict__ Bt, int ldb, long long sBt,
                                                 void* __restrict__ Cv, int ldc, long long sC,
                                                 int M, int N, int K) {
    int koff = 0, Ksub = K;
    if (MODE >= 3) {
        Ksub = K / gridDim.z;
        koff = blockIdx.z * Ksub;
    } else {
        A  += (long long)blockIdx.z * sA;
        Bt += (long long)blockIdx.z * sBt;
    }
    float* Cf = (float*)Cv;
    short* Cs = (short*)Cv;
    Cf += (long long)blockIdx.z * sC;
    Cs += (long long)blockIdx.z * sC;
    const int m0 = blockIdx.y * 128, n0 = blockIdx.x * 128;
    __shared__ short As[2][128 * 64];
    __shared__ short Bs[2][128 * 64];
    const int tid = threadIdx.x, lane = tid & 63, w = tid >> 6;
    const int wm = (w >> 1) * 64, wn = (w & 1) * 64;
    const int drow = lane >> 3;
    const int dcol = ((lane & 7) ^ drow) * 8;
    const short* ag = A + (long long)(m0 + w * 32 + drow) * lda + koff + dcol;
    const short* bg = Bt + (long long)(n0 + w * 32 + drow) * ldb + koff + dcol;
    f32x4 acc[4][4];
    #pragma unroll
    for (int i = 0; i < 4; ++i)
        #pragma unroll
        for (int j = 0; j < 4; ++j) { f32x4 z = {0.f, 0.f, 0.f, 0.f}; acc[i][j] = z; }
    const int ra = lane & 15, quad = lane >> 4;
    const int fs0 = ((quad + 0) ^ (ra & 7)) * 8;
    const int fs1 = ((quad + 4) ^ (ra & 7)) * 8;
    {
        const short* lA = As[0] + w * 32 * 64;
        const short* lB = Bs[0] + w * 32 * 64;
        #pragma unroll
        for (int c = 0; c < 4; ++c) {
            async16(ag + (long long)(c * 8) * lda, lA + c * 512);
            async16(bg + (long long)(c * 8) * ldb, lB + c * 512);
        }
    }
    int cur = 0;
    for (int k0 = 0; k0 < Ksub; k0 += 64) {
        __syncthreads();
        if (k0 + 64 < Ksub) {
            const int nxt = cur ^ 1;
            const short* lA = As[nxt] + w * 32 * 64;
            const short* lB = Bs[nxt] + w * 32 * 64;
            #pragma unroll
            for (int c = 0; c < 4; ++c) {
                async16(ag + (long long)(c * 8) * lda + k0 + 64, lA + c * 512);
                async16(bg + (long long)(c * 8) * ldb + k0 + 64, lB + c * 512);
            }
        }
        const short* cA = As[cur];
        const short* cB = Bs[cur];
        #pragma unroll
        for (int h = 0; h < 2; ++h) {
            const int fs = h ? fs1 : fs0;
            bf8 af[4], bfv[4];
            #pragma unroll
            for (int i = 0; i < 4; ++i) af[i]  = *(const bf8*)(cA + (wm + i * 16 + ra) * 64 + fs);
            #pragma unroll
            for (int j = 0; j < 4; ++j) bfv[j] = *(const bf8*)(cB + (wn + j * 16 + ra) * 64 + fs);
            #pragma unroll
            for (int i = 0; i < 4; ++i)
                #pragma unroll
                for (int j = 0; j < 4; ++j)
                    acc[i][j] = __builtin_amdgcn_mfma_f32_16x16x32_bf16(af[i], bfv[j], acc[i][j], 0, 0, 0);
        }
        cur ^= 1;
    }
    const int cr = quad * 4, cc = ra;
    #pragma unroll
    for (int i = 0; i < 4; ++i) {
        #pragma unroll
        for (int r = 0; r < 4; ++r) {
            int row = m0 + wm + i * 16 + cr + r;
            long long base = (long long)row * ldc + n0 + wn + cc;
            #pragma unroll
            for (int j = 0; j < 4; ++j) {
                float v = acc[i][j][r];
                if (MODE == 2) Cs[base + j * 16] = f2bf(v);
                if (MODE == 3) Cf[base + j * 16] = v;
                if (MODE == 4) Cf[base + j * 16] = Cf[base + j * 16] + v;
            }
        }
    }
}

// ---------------- Fused GEMM + gated activation ----------------
// Tile: 64 M-rows x 256 weight rows, BK=64, double-buffered (R2-proven).
// SWZ: XCD-aware bijective remap for grid (1,32,32). lin = y + 32z round-robins
// across 8 XCDs; remap gives each XCD 4 experts (2 MB of B panels, L2-resident).
// z = (lin&7)*4 + ((lin>>3)&3), y = lin>>5. Deterministic relabeling only.
// gu:  grid (1, 32, 32), SWZ=1: cols z*128, scale = w_route[t][z]
// up:  grid (16, 32, 1), SWZ=0: Bp = wupt + x*256K, cols x*128, no scale
template<bool SCALED, bool SWZ>
__global__ __launch_bounds__(256) void gemm_act(const short* __restrict__ A, int lda,
                                                const short* __restrict__ Bt, long long sBt,
                                                short* __restrict__ Ct, int ldct,
                                                const float* __restrict__ wr) {
    int by = blockIdx.y, bz = blockIdx.z;
    if (SWZ) {
        int lin = blockIdx.y + 32 * blockIdx.z;
        int xcd = lin & 7, idx = lin >> 3;
        bz = (xcd << 2) | (idx & 3);
        by = idx >> 2;
    }
    const short* Bp = Bt + (long long)bz * sBt + (long long)blockIdx.x * (256 * 1024);
    const int cb = (bz * gridDim.x + blockIdx.x) * 128;
    const int m0 = by * 64;
    __shared__ short As[2][64 * 64];
    __shared__ short Bs[2][256 * 64];
    const int tid = threadIdx.x, lane = tid & 63, w = tid >> 6;
    const int wm = (w >> 1) * 32, wn = (w & 1) * 128;
    const int drow = lane >> 3;
    const int dcol = ((lane & 7) ^ drow) * 8;
    const short* ag = A + (long long)(m0 + w * 16 + drow) * lda + dcol;
    const short* bg = Bp + (long long)(w * 64 + drow) * 1024 + dcol;
    f32x4 acc[2][8];
    #pragma unroll
    for (int i = 0; i < 2; ++i)
        #pragma unroll
        for (int j = 0; j < 8; ++j) { f32x4 z = {0.f, 0.f, 0.f, 0.f}; acc[i][j] = z; }
    const int ra = lane & 15, quad = lane >> 4;
    const int fs0 = ((quad + 0) ^ (ra & 7)) * 8;
    const int fs1 = ((quad + 4) ^ (ra & 7)) * 8;
    {
        const short* lA = As[0] + w * 16 * 64;
        const short* lB = Bs[0] + w * 64 * 64;
        async16(ag, lA);
        async16(ag + (long long)8 * lda, lA + 512);
        #pragma unroll
        for (int c = 0; c < 8; ++c)
            async16(bg + (long long)(c * 8) * 1024, lB + c * 512);
    }
    int cur = 0;
    for (int k0 = 0; k0 < 1024; k0 += 64) {
        __syncthreads();
        if (k0 + 64 < 1024) {
            const int nxt = cur ^ 1;
            const short* lA = As[nxt] + w * 16 * 64;
            const short* lB = Bs[nxt] + w * 64 * 64;
            async16(ag + k0 + 64, lA);
            async16(ag + (long long)8 * lda + k0 + 64, lA + 512);
            #pragma unroll
            for (int c = 0; c < 8; ++c)
                async16(bg + (long long)(c * 8) * 1024 + k0 + 64, lB + c * 512);
        }
        const short* cA = As[cur];
        const short* cB = Bs[cur];
        #pragma unroll
        for (int h = 0; h < 2; ++h) {
            const int fs = h ? fs1 : fs0;
            bf8 af0 = *(const bf8*)(cA + (wm + ra) * 64 + fs);
            bf8 af1 = *(const bf8*)(cA + (wm + 16 + ra) * 64 + fs);
            #pragma unroll
            for (int j = 0; j < 8; ++j) {
                bf8 bv = *(const bf8*)(cB + (wn + j * 16 + ra) * 64 + fs);
                acc[0][j] = __builtin_amdgcn_mfma_f32_16x16x32_bf16(af0, bv, acc[0][j], 0, 0, 0);
                acc[1][j] = __builtin_amdgcn_mfma_f32_16x16x32_bf16(af1, bv, acc[1][j], 0, 0, 0);
            }
        }
        cur ^= 1;
    }
    #pragma unroll
    for (int i = 0; i < 2; ++i)
        #pragma unroll
        for (int r = 0; r < 4; ++r) {
            int token = m0 + wm + i * 16 + quad * 4 + r;
            float scale = SCALED ? wr[token * NEXP + bz] : 1.0f;
            #pragma unroll
            for (int jp = 0; jp < 4; ++jp) {
                float g = acc[i][2 * jp][r];
                float u = acc[i][2 * jp + 1][r];
                float v = g / (1.0f + __expf(-g)) * u * scale;
                Ct[(long long)token * ldct + cb + wn / 2 + jp * 16 + ra] = f2bf(v);
            }
        }
}

// ---------------- combine: dst = add + sum of 4 fp32 slices ----------------
__global__ void combine4(const float* __restrict__ slices, const float* __restrict__ add,
                         float* __restrict__ dst) {
    long long i = (long long)blockIdx.x * 256 + threadIdx.x;
    const long long S4 = (long long)TOKENS * DIM / 4;
    float4 s = ((const float4*)add)[i];
    #pragma unroll
    for (int c = 0; c < 4; ++c) {
        float4 p = ((const float4*)slices)[c * S4 + i];
        s.x += p.x; s.y += p.y; s.z += p.z; s.w += p.w;
    }
    ((float4*)dst)[i] = s;
}

// ---------------- combine 4 slices + residual -> xffn fp32 AND rmsnorm -> bf16 -------
__global__ __launch_bounds__(256) void combine_rms(const float* __restrict__ slices,
                                                   const float* __restrict__ add,
                                                   const float* __restrict__ w,
                                                   float* __restrict__ xffn,
                                                   short* __restrict__ xf) {
    int row = blockIdx.x, t = threadIdx.x;
    long long i = (long long)row * 256 + t;
    const long long S4 = (long long)TOKENS * DIM / 4;
    float4 s = ((const float4*)add)[i];
    #pragma unroll
    for (int c = 0; c < 4; ++c) {
        float4 p = ((const float4*)slices)[c * S4 + i];
        s.x += p.x; s.y += p.y; s.z += p.z; s.w += p.w;
    }
    ((float4*)xffn)[i] = s;
    float ss = s.x*s.x + s.y*s.y + s.z*s.z + s.w*s.w;
    #pragma unroll
    for (int off = 32; off; off >>= 1) ss += __shfl_down(ss, off);
    __shared__ float warps[4];
    if ((t & 63) == 0) warps[t >> 6] = ss;
    __syncthreads();
    float tot = warps[0] + warps[1] + warps[2] + warps[3];
    float scale = rsqrtf(tot / (float)DIM + EPS_);
    float4 wv = ((const float4*)w)[t];
    short4 o;
    o.x = f2bf(s.x * scale * wv.x);
    o.y = f2bf(s.y * scale * wv.y);
    o.z = f2bf(s.z * scale * wv.z);
    o.w = f2bf(s.w * scale * wv.w);
    ((short4*)(xf + (long long)row * DIM))[t] = o;
}

// ---------------- QKV post (bf16 qkv): split heads, l2norm(q,k), RoPE -> bf16 [h][s][64] ----
__global__ __launch_bounds__(256) void qkv_post(const short* __restrict__ qkv,
                                                short* __restrict__ q,
                                                short* __restrict__ k) {
    int lane = threadIdx.x & 63;
    int sh = blockIdx.x * 4 + (threadIdx.x >> 6);
    int s = sh >> 4;
    int h = sh & 15;
    const short* base = qkv + (long long)s * 3 * DIM;
    float qv = bf2f(base[h * HEADDIM + lane]);
    float kv = bf2f(base[DIM + h * HEADDIM + lane]);
    float qs = qv * qv, ks = kv * kv;
    #pragma unroll
    for (int off = 32; off; off >>= 1) {
        qs += __shfl_xor(qs, off);
        ks += __shfl_xor(ks, off);
    }
    qv /= fmaxf(sqrtf(qs), EPS_);
    kv /= fmaxf(sqrtf(ks), EPS_);
    int i = lane & 31;
    float f = (float)s * powf(10000.0f, -(float)i / 32.0f);
    float c = cosf(f), sn = sinf(f);
    float qo = __shfl_xor(qv, 32);
    float ko = __shfl_xor(kv, 32);
    float sgn = (lane < 32) ? sn : -sn;
    float qr = qv * c + qo * sgn;
    float kr = kv * c + ko * sgn;
    long long o = ((long long)h * TOKENS + s) * HEADDIM + lane;
    q[o] = f2bf(qr);
    k[o] = f2bf(kr);
}

// ---------------- V transpose (bf16 qkv): [s][3D] -> vt bf16 [h][64][2048] ----------------
__global__ __launch_bounds__(256) void vtrans(const short* __restrict__ qkv,
                                              short* __restrict__ vt) {
    int h = blockIdx.z;
    int s0 = blockIdx.x * 32, d0 = blockIdx.y * 32;
    __shared__ short t[32][34];
    int tx = threadIdx.x & 31, ty = threadIdx.x >> 5;
    #pragma unroll
    for (int r = ty; r < 32; r += 8)
        t[r][tx] = qkv[(long long)(s0 + r) * (3 * DIM) + 2 * DIM + h * HEADDIM + d0 + tx];
    __syncthreads();
    #pragma unroll
    for (int r = ty; r < 32; r += 8)
        vt[((long long)h * HEADDIM + d0 + r) * TOKENS + s0 + tx] = t[tx][r];
}

// ---------------- MFMA flash attention: LDS-staged K/V (DMA), key-split combine ----------
#define PLD 68
__global__ __launch_bounds__(256) void attn_kernel(const short* __restrict__ q,
                                                   const short* __restrict__ k,
                                                   const short* __restrict__ vt,
                                                   float* __restrict__ Oacc,
                                                   float* __restrict__ lacc) {
    const int w = threadIdx.x >> 6, lane = threadIdx.x & 63;
    const int col = lane & 15, quad = lane >> 4;
    const int head = blockIdx.x / 80;
    const int t = blockIdx.x % 80;
    int qb, ch;
    if (t < 8)       { qb = t;                ch = 0; }
    else if (t < 24) { qb = 8 + (t - 8) / 2;  ch = (t - 8) % 2; }
    else if (t < 48) { qb = 16 + (t - 24) / 3; ch = (t - 24) % 3; }
    else             { qb = 24 + (t - 48) / 4; ch = (t - 48) % 4; }
    const int nch = qb / 8 + 1;
    const int ntk = qb + 1;
    const int per = (ntk + nch - 1) / nch;
    const int t0 = ch * per;
    const int t1 = (t0 + per < ntk) ? t0 + per : ntk;
    const int qbase = qb * 64 + w * 16;
    __shared__ short Ks[64 * 64];
    __shared__ short Vs[64 * 64];
    __shared__ short Ps[4 * 16 * PLD];
    short* Pw = Ps + w * 16 * PLD;
    const short* kh = k + (long long)head * TOKENS * HEADDIM;
    const short* vh = vt + (long long)head * HEADDIM * TOKENS;
    const int r8 = lane >> 3;
    const int sw = ((lane & 7) ^ r8) * 8;
    bf8 qf[2];
    #pragma unroll
    for (int ks = 0; ks < 2; ++ks)
        qf[ks] = *(const bf8*)(q + ((long long)head * TOKENS + qbase + col) * HEADDIM + ks * 32 + quad * 8);
    const int fo0 = (((0 * 4) + quad) ^ (col & 7)) * 8;
    const int fo1 = (((1 * 4) + quad) ^ (col & 7)) * 8;
    f32x4 o_[4];
    float l_[4];
    #pragma unroll
    for (int n = 0; n < 4; ++n) { f32x4 z = {0.f, 0.f, 0.f, 0.f}; o_[n] = z; }
    #pragma unroll
    for (int r = 0; r < 4; ++r) l_[r] = 0.f;
    for (int kt = t0; kt < t1; ++kt) {
        const int j0 = kt * 64;
        #pragma unroll
        for (int c = 0; c < 2; ++c) {
            int row = w * 16 + c * 8 + r8;
            async16(kh + (long long)(j0 + row) * HEADDIM + sw, Ks + (w * 16 + c * 8) * 64 + lane * 8);
            async16(vh + (long long)row * TOKENS + j0 + sw, Vs + (w * 16 + c * 8) * 64 + lane * 8);
        }
        __syncthreads();
        f32x4 sacc[4];
        #pragma unroll
        for (int n = 0; n < 4; ++n) { f32x4 z = {0.f, 0.f, 0.f, 0.f}; sacc[n] = z; }
        #pragma unroll
        for (int ks = 0; ks < 2; ++ks) {
            const int fo = ks ? fo1 : fo0;
            #pragma unroll
            for (int nt = 0; nt < 4; ++nt) {
                bf8 kf = *(const bf8*)(Ks + (nt * 16 + col) * 64 + fo);
                sacc[nt] = __builtin_amdgcn_mfma_f32_16x16x32_bf16(qf[ks], kf, sacc[nt], 0, 0, 0);
            }
        }
        const bool diag = (j0 + 64 > qbase);
        #pragma unroll
        for (int nt = 0; nt < 4; ++nt)
            #pragma unroll
            for (int r = 0; r < 4; ++r) {
                float p = __expf(sacc[nt][r] * 0.125f);
                if (diag && (j0 + nt * 16 + col > qbase + quad * 4 + r)) p = 0.f;
                l_[r] += p;
                Pw[(quad * 4 + r) * PLD + nt * 16 + col] = f2bf(p);
            }
        #pragma unroll
        for (int ks = 0; ks < 2; ++ks) {
            bf8 pf = *(const bf8*)(Pw + col * PLD + ks * 32 + quad * 8);
            const int fo = ks ? fo1 : fo0;
            #pragma unroll
            for (int nt = 0; nt < 4; ++nt) {
                bf8 vf = *(const bf8*)(Vs + (nt * 16 + col) * 64 + fo);
                o_[nt] = __builtin_amdgcn_mfma_f32_16x16x32_bf16(pf, vf, o_[nt], 0, 0, 0);
            }
        }
        __syncthreads();
    }
    float* Oc = Oacc + (long long)ch * (TOKENS * DIM);
    #pragma unroll
    for (int r = 0; r < 4; ++r) {
        int row = qbase + quad * 4 + r;
        float* op = Oc + (long long)row * DIM + head * HEADDIM;
        #pragma unroll
        for (int nt = 0; nt < 4; ++nt)
            op[nt * 16 + col] = o_[nt][r];
        float l = l_[r];
        #pragma unroll
        for (int off = 1; off < 16; off <<= 1) l += __shfl_xor(l, off);
        if (col == 0) lacc[ch * (TOKENS * NHEADS) + row * NHEADS + head] = l;
    }
}

// ---------------- Attention normalize: xo = sum_ch Oacc / sum_ch l -> bf16 ----------------
__global__ void attn_norm(const float* __restrict__ Oacc, const float* __restrict__ lacc,
                          short* __restrict__ xo) {
    long long i = (long long)blockIdx.x * 256 + threadIdx.x;  // 2M
    int row = (int)(i >> 10), col = (int)(i & 1023);
    int nch = (row >> 9) + 1;
    int head = col >> 6;
    float so = 0.f, sl = 0.f;
    for (int c = 0; c < nch; ++c) {
        so += Oacc[(long long)c * (TOKENS * DIM) + i];
        sl += lacc[c * (TOKENS * NHEADS) + row * NHEADS + head];
    }
    xo[i] = f2bf(so / sl);
}

// ---------------- Router (bf16 x input) ----------------
__global__ __launch_bounds__(256) void router_kernel(const short* __restrict__ xf,
                                                     const float* __restrict__ keys_w,
                                                     const int* __restrict__ idx,
                                                     const float* __restrict__ vals,
                                                     float* __restrict__ w_route) {
    int t = blockIdx.x;
    int tid = threadIdx.x;
    int e = tid & 31, c = tid >> 5;
    const short* xr = xf + (long long)t * DIM;
    float p = 0.f;
    for (int j = 0; j < 128; ++j)
        p += bf2f(xr[c * 128 + j]) * keys_w[(c * 128 + j) * NEXP + e];
    __shared__ float part[8][32];
    part[c][e] = p;
    __syncthreads();
    if (tid < NEXP) {
        float lg = 0.f;
        #pragma unroll
        for (int cc = 0; cc < 8; ++cc) lg += part[cc][tid];
        part[0][tid] = lg;
    }
    __syncthreads();
    __shared__ float gate_s[TOPK];
    __shared__ int idx_s[TOPK];
    if (tid < TOPK) {
        int ii = idx[t * TOPK + tid];
        float g = vals[t * TOPK + tid] + part[0][ii];
        gate_s[tid] = (1.0f / (1.0f + __expf(-g))) * RSF_;
        idx_s[tid] = ii;
    }
    __syncthreads();
    if (tid < NEXP) {
        float wr = 0.f;
        #pragma unroll
        for (int kk = 0; kk < TOPK; ++kk)
            if (idx_s[kk] == tid) wr += gate_s[kk];
        w_route[(long long)t * NEXP + tid] = wr;
    }
}

extern "C" void kernel_launch(void* const* d_in, const int* in_sizes, int n_in,
                              void* d_out, int out_size, void* d_ws, size_t ws_size,
                              hipStream_t stream) {
    (void)in_sizes; (void)n_in; (void)out_size; (void)ws_size;
    const float* x_input     = (const float*)d_in[0];
    const int*   indices     = (const int*)d_in[1];
    const float* values      = (const float*)d_in[2];
    const float* w_attn      = (const float*)d_in[3];
    const float* w_attn_o    = (const float*)d_in[4];
    const float* attn_norm_w = (const float*)d_in[5];
    const float* ffn_norm_w  = (const float*)d_in[6];
    const float* ffn_experts = (const float*)d_in[7];
    const float* keys_w      = (const float*)d_in[8];
    const float* w_up        = (const float*)d_in[9];
    const float* w_down      = (const float*)d_in[10];
    float* out = (float*)d_out;
    float* ws  = (float*)d_ws;

    const long long M1 = 1024 * 1024;
    const long long SLICE = (long long)TOKENS * DIM;  // 2M floats
    // Workspace map, M1-float units. TRUE extents (2M bf16 = 4 MiB = 1.0 M1 — the
    // old map undersized bf16 buffers 2x; q/k/vt overlapped). All live ranges
    // disjoint now; max extent 24 M1 = 96 MB.
    float* xffn    = ws + 0 * M1;                     // [0,2)    fp32, whole call
    short* xa_bf   = (short*)(ws + 2 * M1);           // [2,3)    phase A
    short* xf_bf   = (short*)(ws + 3 * M1);           // [3,4)    combine_rms..phase C
    short* xattn_bf= (short*)(ws + 4 * M1);           // [4,5)    phase A
    float* w_route = ws + 5 * M1;                     // [5,5.07)
    float* Oacc    = ws + 6 * M1;                     // [6,14)   phase A
    float* lacc    = ws + 14 * M1;                    // [14,14.13) phase A
    short* qh_bf   = (short*)(ws + 15 * M1);          // [15,16)  1 M1 (2M bf16)
    short* kh_bf   = (short*)(ws + 16 * M1);          // [16,17)  1 M1
    short* vt_bf   = (short*)(ws + 17 * M1);          // [17,18)  1 M1
    short* wattn_t = (short*)(ws + 18 * M1);          // [18,19.5) 1.5 M1 (3M bf16)
    short* wattno_t= (short*)(ws + 19 * M1 + M1 / 2); // [19.5,20) 0.5 M1 (1M bf16)
    short* qkv_bf  = (short*)(ws + 21 * M1);          // [21,24)  3 M1, dead after vtrans
    float* oslice  = ws + 6 * M1;                     // [6,14)   (Oacc dead after attn_norm)
    short* wgu     = (short*)(ws + 6 * M1);           // [6,10)   phase B (oslice dead)
    short* h_bf    = (short*)(ws + 10 * M1);          // [10,14)
    short* w2t     = (short*)(ws + 14 * M1);          // [14,16)  (lacc, qh dead)
    float* yslice  = ws + 16 * M1;                    // [16,24)  (kh/vt/wattn_t/wattno_t/qkv dead)
    short* wupt    = (short*)(ws + 6 * M1);           // [6,8)    phase C (wgu dead)
    short* hs_bf   = (short*)(ws + 8 * M1);           // [8,10)
    short* wdownt  = (short*)(ws + 10 * M1);          // [10,11)  (h_bf dead)

    // ---- phase A: attention ----
    tconv<<<dim3(3072 / 32, DIM / 32, 1), 256, 0, stream>>>(w_attn, 0, wattn_t, 0, DIM, 3 * DIM);
    rmsnorm_kernel<<<TOKENS, 256, 0, stream>>>(x_input, attn_norm_w, xa_bf);
    gemm_bf16<2><<<dim3(3072 / 128, TOKENS / 128, 1), 256, 0, stream>>>(
        xa_bf, DIM, 0, wattn_t, DIM, 0, qkv_bf, 3 * DIM, 0, TOKENS, 3 * DIM, DIM);
    qkv_post<<<(TOKENS * NHEADS) / 4, 256, 0, stream>>>(qkv_bf, qh_bf, kh_bf);
    vtrans<<<dim3(TOKENS / 32, HEADDIM / 32, NHEADS), 256, 0, stream>>>(qkv_bf, vt_bf);
    attn_kernel<<<NHEADS * 80, 256, 0, stream>>>(qh_bf, kh_bf, vt_bf, Oacc, lacc);
    attn_norm<<<(TOKENS * DIM) / 256, 256, 0, stream>>>(Oacc, lacc, xattn_bf);
    tconv<<<dim3(DIM / 32, DIM / 32, 1), 256, 0, stream>>>(w_attn_o, 0, wattno_t, 0, DIM, DIM);
    gemm_bf16<3><<<dim3(DIM / 128, TOKENS / 128, 4), 256, 0, stream>>>(
        xattn_bf, DIM, 0, wattno_t, DIM, 0, oslice, DIM, SLICE, TOKENS, DIM, DIM);
    // xffn = x_input + sum(oslice); xf_bf = rmsnorm(xffn) -- fused
    combine_rms<<<TOKENS, 256, 0, stream>>>(oslice, x_input, ffn_norm_w, xffn, xf_bf);

    // ---- phase B: router + experts ----
    router_kernel<<<TOKENS, 256, 0, stream>>>(xf_bf, keys_w, indices, values, w_route);
    guconv<<<dim3(EDIM / 32, DIM / 32, 2 * NEXP), 256, 0, stream>>>(ffn_experts, wgu);
    gemm_act<true, true><<<dim3(1, TOKENS / 64, NEXP), 256, 0, stream>>>(
        xf_bf, DIM, wgu, 256 * 1024, h_bf, NEXP * EDIM, w_route);
    w2conv<<<(NEXP * DIM * EDIM) / 256, 256, 0, stream>>>(
        ffn_experts + 2LL * NEXP * DIM * EDIM, w2t);
    gemm_bf16<3><<<dim3(DIM / 128, TOKENS / 128, 4), 256, 0, stream>>>(
        h_bf, NEXP * EDIM, 0, w2t, NEXP * EDIM, 0, yslice, DIM, SLICE, TOKENS, DIM, NEXP * EDIM);

    // ---- phase C: shared expert ----
    upconv<<<dim3((2 * DSHARED) / 32, DIM / 32, 1), 256, 0, stream>>>(w_up, wupt);
    gemm_act<false, false><<<dim3((2 * DSHARED) / 256, TOKENS / 64, 1), 256, 0, stream>>>(
        xf_bf, DIM, wupt, 0, hs_bf, DSHARED, nullptr);
    tconv<<<dim3(DIM / 32, DSHARED / 32, 1), 256, 0, stream>>>(w_down, 0, wdownt, 0, DSHARED, DIM);
    gemm_bf16<4><<<dim3(DIM / 128, TOKENS / 128, 4), 256, 0, stream>>>(
        hs_bf, DSHARED, 0, wdownt, DSHARED, 0, yslice, DIM, SLICE, TOKENS, DIM, DSHARED);

    // ---- final: out = xffn + sum of 4 slices ----
    combine4<<<(TOKENS * DIM) / 1024, 256, 0, stream>>>(yslice, xffn, out);
}

// Round 10
// 391.120 us; speedup vs baseline: 1.1103x; 1.0417x over previous
//
#include <hip/hip_runtime.h>
#include <math.h>

#define TOKENS 2048
#define DIM 1024
#define NHEADS 16
#define HEADDIM 64
#define NEXP 32
#define EDIM 128
#define TOPK 8
#define DSHARED 2048
#define RSF_ 2.5f
#define EPS_ 1e-6f

using bf8  = __attribute__((ext_vector_type(8))) short;   // 8 bf16 in 4 VGPRs
using f32x4 = __attribute__((ext_vector_type(4))) float;  // MFMA accumulator

__device__ __forceinline__ short f2bf(float f) {
    unsigned u = __float_as_uint(f);
    unsigned r = (u + 0x7fffu + ((u >> 16) & 1u)) >> 16;
    return (short)r;
}
__device__ __forceinline__ float bf2f(short s) {
    return __uint_as_float(((unsigned)(unsigned short)s) << 16);
}

// Direct global->LDS DMA, 16B per lane. LDS dest = wave-uniform base + lane*16.
__device__ __forceinline__ void async16(const short* g, const short* l) {
    __builtin_amdgcn_global_load_lds(
        (const __attribute__((address_space(1))) void*)(unsigned long long)g,
        (__attribute__((address_space(3))) void*)(unsigned)(unsigned long long)l,
        16, 0, 0);
}

// ---------------- RMSNorm: one block per token, bf16 output ----------------
__global__ __launch_bounds__(256) void rmsnorm_kernel(const float* __restrict__ x,
                                                      const float* __restrict__ w,
                                                      short* __restrict__ out) {
    int row = blockIdx.x;
    const float* xr = x + (long long)row * DIM;
    int t = threadIdx.x;
    float4 xv = ((const float4*)xr)[t];
    float ss = xv.x*xv.x + xv.y*xv.y + xv.z*xv.z + xv.w*xv.w;
    #pragma unroll
    for (int off = 32; off; off >>= 1) ss += __shfl_down(ss, off);
    __shared__ float warps[4];
    if ((t & 63) == 0) warps[t >> 6] = ss;
    __syncthreads();
    float tot = warps[0] + warps[1] + warps[2] + warps[3];
    float scale = rsqrtf(tot / (float)DIM + EPS_);
    float4 wv = ((const float4*)w)[t];
    short4 o;
    o.x = f2bf(xv.x * scale * wv.x);
    o.y = f2bf(xv.y * scale * wv.y);
    o.z = f2bf(xv.z * scale * wv.z);
    o.w = f2bf(xv.w * scale * wv.w);
    ((short4*)(out + (long long)row * DIM))[t] = o;
}

// ---------------- Transpose + convert: fp32 in[K][N] -> bf16 out[N][K] ----------------
__global__ __launch_bounds__(256) void tconv(const float* __restrict__ in, long long sin,
                                             short* __restrict__ out, long long sout,
                                             int K, int N) {
    in  += (long long)blockIdx.z * sin;
    out += (long long)blockIdx.z * sout;
    __shared__ float t[32][33];
    int n0 = blockIdx.x * 32, k0 = blockIdx.y * 32;
    int tx = threadIdx.x & 31, ty = threadIdx.x >> 5;  // ty 0..7
    #pragma unroll
    for (int r = ty; r < 32; r += 8)
        t[r][tx] = in[(long long)(k0 + r) * N + n0 + tx];
    __syncthreads();
    #pragma unroll
    for (int r = ty; r < 32; r += 8)
        out[(long long)(n0 + r) * K + k0 + tx] = f2bf(t[tx][r]);
}

// ---------------- Merged expert/shared weight conversions (one launch) ----------------
// Block ranges (1-D grid, 30720 blocks):
// [0,8192):      guconv  — W0/W1 [e][k][c] fp32 -> wgu'[e] rows rr=(c>>4)*32+hf*16+(c&15)
// [8192,24576):  w2conv  — W2 [e][d][h] fp32 -> w2t bf16 [d][e*128+h]
// [24576,28672): upconv  — w_up [1024][4096] fp32 -> wupt' interleaved rows
// [28672,30720): wdconv  — w_down [2048][1024] fp32 -> wdownt bf16 [n][k] (transpose)
__global__ __launch_bounds__(256) void wconv_merged(const float* __restrict__ ex,
                                                    const float* __restrict__ wup,
                                                    const float* __restrict__ wdown,
                                                    short* __restrict__ wgu,
                                                    short* __restrict__ w2t,
                                                    short* __restrict__ wupt,
                                                    short* __restrict__ wdownt) {
    const int b = blockIdx.x;
    const int tid = threadIdx.x;
    __shared__ float t[32][33];
    const int tx = tid & 31, ty = tid >> 5;
    if (b < 8192) {
        // guconv: z = b>>7 in [0,64), rem = b&127: bx = rem&3, by = rem>>2
        int z = b >> 7, rem = b & 127;
        int n0 = (rem & 3) * 32, k0 = (rem >> 2) * 32;
        int e = z & 31, hf = z >> 5;
        const float* in = ex + (long long)hf * (NEXP * DIM * EDIM) + (long long)e * (DIM * EDIM);
        short* outp = wgu + (long long)e * (256 * 1024);
        #pragma unroll
        for (int r = ty; r < 32; r += 8)
            t[r][tx] = in[(long long)(k0 + r) * EDIM + n0 + tx];
        __syncthreads();
        #pragma unroll
        for (int r = ty; r < 32; r += 8) {
            int c = n0 + r;
            int rr = ((c >> 4) << 5) + hf * 16 + (c & 15);
            outp[(long long)rr * 1024 + k0 + tx] = f2bf(t[tx][r]);
        }
        return;
    }
    if (b < 24576) {
        long long i = (long long)(b - 8192) * 256 + tid;  // 4M
        const float* in2 = ex + 2LL * NEXP * DIM * EDIM;
        int e = (int)(i >> 17);
        int d = (int)(i >> 7) & 1023;
        int h = (int)(i & 127);
        w2t[(long long)d * (NEXP * EDIM) + e * EDIM + h] = f2bf(in2[i]);
        return;
    }
    if (b < 28672) {
        // upconv: u = b-24576: bx = u&127, by = u>>7
        int u = b - 24576;
        int n0 = (u & 127) * 32, k0 = (u >> 7) * 32;
        #pragma unroll
        for (int r = ty; r < 32; r += 8)
            t[r][tx] = wup[(long long)(k0 + r) * (2 * DSHARED) + n0 + tx];
        __syncthreads();
        #pragma unroll
        for (int r = ty; r < 32; r += 8) {
            int n = n0 + r;
            int hf = n >> 11, c2 = n & 2047;
            int rr = ((c2 >> 7) << 8) + (((c2 & 127) >> 4) << 5) + hf * 16 + (c2 & 15);
            wupt[(long long)rr * 1024 + k0 + tx] = f2bf(t[tx][r]);
        }
        return;
    }
    // wdconv: v = b-28672: bx = v&31, by = v>>5; K=DSHARED(2048), N=DIM(1024)
    int v = b - 28672;
    int n0 = (v & 31) * 32, k0 = (v >> 5) * 32;
    #pragma unroll
    for (int r = ty; r < 32; r += 8)
        t[r][tx] = wdown[(long long)(k0 + r) * DIM + n0 + tx];
    __syncthreads();
    #pragma unroll
    for (int r = ty; r < 32; r += 8)
        wdownt[(long long)(n0 + r) * DSHARED + k0 + tx] = f2bf(t[tx][r]);
}

// ---------------- bf16 MFMA GEMM: C[M][N] = A[M][K] @ Bt[N][K]^T ----------------
// 128x128 tile, BK=64, XOR-swizzled LDS, async global->LDS staging, double-buffered.
// MODE 2: bf16 store, z = batch.
// MODE 3: f32 store, z = K-split slice (sC = slice stride). No atomics.
// MODE 4: f32 read+add+store, z = K-split slice (block-exclusive tiles).
template<int MODE>
__global__ __launch_bounds__(256) void gemm_bf16(const short* __restrict__ A, int lda, long long sA,
                                                 const short* __restrict__ Bt, int ldb, long long sBt,
                                                 void* __restrict__ Cv, int ldc, long long sC,
                                                 int M, int N, int K) {
    int koff = 0, Ksub = K;
    if (MODE >= 3) {
        Ksub = K / gridDim.z;
        koff = blockIdx.z * Ksub;
    } else {
        A  += (long long)blockIdx.z * sA;
        Bt += (long long)blockIdx.z * sBt;
    }
    float* Cf = (float*)Cv;
    short* Cs = (short*)Cv;
    Cf += (long long)blockIdx.z * sC;
    Cs += (long long)blockIdx.z * sC;
    const int m0 = blockIdx.y * 128, n0 = blockIdx.x * 128;
    __shared__ short As[2][128 * 64];
    __shared__ short Bs[2][128 * 64];
    const int tid = threadIdx.x, lane = tid & 63, w = tid >> 6;
    const int wm = (w >> 1) * 64, wn = (w & 1) * 64;
    const int drow = lane >> 3;
    const int dcol = ((lane & 7) ^ drow) * 8;
    const short* ag = A + (long long)(m0 + w * 32 + drow) * lda + koff + dcol;
    const short* bg = Bt + (long long)(n0 + w * 32 + drow) * ldb + koff + dcol;
    f32x4 acc[4][4];
    #pragma unroll
    for (int i = 0; i < 4; ++i)
        #pragma unroll
        for (int j = 0; j < 4; ++j) { f32x4 z = {0.f, 0.f, 0.f, 0.f}; acc[i][j] = z; }
    const int ra = lane & 15, quad = lane >> 4;
    const int fs0 = ((quad + 0) ^ (ra & 7)) * 8;
    const int fs1 = ((quad + 4) ^ (ra & 7)) * 8;
    {
        const short* lA = As[0] + w * 32 * 64;
        const short* lB = Bs[0] + w * 32 * 64;
        #pragma unroll
        for (int c = 0; c < 4; ++c) {
            async16(ag + (long long)(c * 8) * lda, lA + c * 512);
            async16(bg + (long long)(c * 8) * ldb, lB + c * 512);
        }
    }
    int cur = 0;
    for (int k0 = 0; k0 < Ksub; k0 += 64) {
        __syncthreads();
        if (k0 + 64 < Ksub) {
            const int nxt = cur ^ 1;
            const short* lA = As[nxt] + w * 32 * 64;
            const short* lB = Bs[nxt] + w * 32 * 64;
            #pragma unroll
            for (int c = 0; c < 4; ++c) {
                async16(ag + (long long)(c * 8) * lda + k0 + 64, lA + c * 512);
                async16(bg + (long long)(c * 8) * ldb + k0 + 64, lB + c * 512);
            }
        }
        const short* cA = As[cur];
        const short* cB = Bs[cur];
        #pragma unroll
        for (int h = 0; h < 2; ++h) {
            const int fs = h ? fs1 : fs0;
            bf8 af[4], bfv[4];
            #pragma unroll
            for (int i = 0; i < 4; ++i) af[i]  = *(const bf8*)(cA + (wm + i * 16 + ra) * 64 + fs);
            #pragma unroll
            for (int j = 0; j < 4; ++j) bfv[j] = *(const bf8*)(cB + (wn + j * 16 + ra) * 64 + fs);
            #pragma unroll
            for (int i = 0; i < 4; ++i)
                #pragma unroll
                for (int j = 0; j < 4; ++j)
                    acc[i][j] = __builtin_amdgcn_mfma_f32_16x16x32_bf16(af[i], bfv[j], acc[i][j], 0, 0, 0);
        }
        cur ^= 1;
    }
    const int cr = quad * 4, cc = ra;
    #pragma unroll
    for (int i = 0; i < 4; ++i) {
        #pragma unroll
        for (int r = 0; r < 4; ++r) {
            int row = m0 + wm + i * 16 + cr + r;
            long long base = (long long)row * ldc + n0 + wn + cc;
            #pragma unroll
            for (int j = 0; j < 4; ++j) {
                float v = acc[i][j][r];
                if (MODE == 2) Cs[base + j * 16] = f2bf(v);
                if (MODE == 3) Cf[base + j * 16] = v;
                if (MODE == 4) Cf[base + j * 16] = Cf[base + j * 16] + v;
            }
        }
    }
}

// ---------------- Fused GEMM + gated activation ----------------
// Tile: 64 M-rows x 256 weight rows, BK=64, double-buffered (R2-proven).
// SWZ: XCD-aware bijective remap for grid (1,32,32). lin = y + 32z round-robins
// across 8 XCDs; remap gives each XCD 4 experts (2 MB of B panels, L2-resident).
// z = (lin&7)*4 + ((lin>>3)&3), y = lin>>5. Deterministic relabeling only.
// gu:  grid (1, 32, 32), SWZ=1: cols z*128, scale = w_route[t][z]
// up:  grid (16, 32, 1), SWZ=0: Bp = wupt + x*256K, cols x*128, no scale
template<bool SCALED, bool SWZ>
__global__ __launch_bounds__(256) void gemm_act(const short* __restrict__ A, int lda,
                                                const short* __restrict__ Bt, long long sBt,
                                                short* __restrict__ Ct, int ldct,
                                                const float* __restrict__ wr) {
    int by = blockIdx.y, bz = blockIdx.z;
    if (SWZ) {
        int lin = blockIdx.y + 32 * blockIdx.z;
        int xcd = lin & 7, idx = lin >> 3;
        bz = (xcd << 2) | (idx & 3);
        by = idx >> 2;
    }
    const short* Bp = Bt + (long long)bz * sBt + (long long)blockIdx.x * (256 * 1024);
    const int cb = (bz * gridDim.x + blockIdx.x) * 128;
    const int m0 = by * 64;
    __shared__ short As[2][64 * 64];
    __shared__ short Bs[2][256 * 64];
    const int tid = threadIdx.x, lane = tid & 63, w = tid >> 6;
    const int wm = (w >> 1) * 32, wn = (w & 1) * 128;
    const int drow = lane >> 3;
    const int dcol = ((lane & 7) ^ drow) * 8;
    const short* ag = A + (long long)(m0 + w * 16 + drow) * lda + dcol;
    const short* bg = Bp + (long long)(w * 64 + drow) * 1024 + dcol;
    f32x4 acc[2][8];
    #pragma unroll
    for (int i = 0; i < 2; ++i)
        #pragma unroll
        for (int j = 0; j < 8; ++j) { f32x4 z = {0.f, 0.f, 0.f, 0.f}; acc[i][j] = z; }
    const int ra = lane & 15, quad = lane >> 4;
    const int fs0 = ((quad + 0) ^ (ra & 7)) * 8;
    const int fs1 = ((quad + 4) ^ (ra & 7)) * 8;
    {
        const short* lA = As[0] + w * 16 * 64;
        const short* lB = Bs[0] + w * 64 * 64;
        async16(ag, lA);
        async16(ag + (long long)8 * lda, lA + 512);
        #pragma unroll
        for (int c = 0; c < 8; ++c)
            async16(bg + (long long)(c * 8) * 1024, lB + c * 512);
    }
    int cur = 0;
    for (int k0 = 0; k0 < 1024; k0 += 64) {
        __syncthreads();
        if (k0 + 64 < 1024) {
            const int nxt = cur ^ 1;
            const short* lA = As[nxt] + w * 16 * 64;
            const short* lB = Bs[nxt] + w * 64 * 64;
            async16(ag + k0 + 64, lA);
            async16(ag + (long long)8 * lda + k0 + 64, lA + 512);
            #pragma unroll
            for (int c = 0; c < 8; ++c)
                async16(bg + (long long)(c * 8) * 1024 + k0 + 64, lB + c * 512);
        }
        const short* cA = As[cur];
        const short* cB = Bs[cur];
        #pragma unroll
        for (int h = 0; h < 2; ++h) {
            const int fs = h ? fs1 : fs0;
            bf8 af0 = *(const bf8*)(cA + (wm + ra) * 64 + fs);
            bf8 af1 = *(const bf8*)(cA + (wm + 16 + ra) * 64 + fs);
            #pragma unroll
            for (int j = 0; j < 8; ++j) {
                bf8 bv = *(const bf8*)(cB + (wn + j * 16 + ra) * 64 + fs);
                acc[0][j] = __builtin_amdgcn_mfma_f32_16x16x32_bf16(af0, bv, acc[0][j], 0, 0, 0);
                acc[1][j] = __builtin_amdgcn_mfma_f32_16x16x32_bf16(af1, bv, acc[1][j], 0, 0, 0);
            }
        }
        cur ^= 1;
    }
    #pragma unroll
    for (int i = 0; i < 2; ++i)
        #pragma unroll
        for (int r = 0; r < 4; ++r) {
            int token = m0 + wm + i * 16 + quad * 4 + r;
            float scale = SCALED ? wr[token * NEXP + bz] : 1.0f;
            #pragma unroll
            for (int jp = 0; jp < 4; ++jp) {
                float g = acc[i][2 * jp][r];
                float u = acc[i][2 * jp + 1][r];
                float v = g / (1.0f + __expf(-g)) * u * scale;
                Ct[(long long)token * ldct + cb + wn / 2 + jp * 16 + ra] = f2bf(v);
            }
        }
}

// ---------------- combine: dst = add + sum of 4 fp32 slices ----------------
__global__ void combine4(const float* __restrict__ slices, const float* __restrict__ add,
                         float* __restrict__ dst) {
    long long i = (long long)blockIdx.x * 256 + threadIdx.x;
    const long long S4 = (long long)TOKENS * DIM / 4;
    float4 s = ((const float4*)add)[i];
    #pragma unroll
    for (int c = 0; c < 4; ++c) {
        float4 p = ((const float4*)slices)[c * S4 + i];
        s.x += p.x; s.y += p.y; s.z += p.z; s.w += p.w;
    }
    ((float4*)dst)[i] = s;
}

// ---------------- combine 4 slices + residual -> xffn fp32 AND rmsnorm -> bf16 -------
__global__ __launch_bounds__(256) void combine_rms(const float* __restrict__ slices,
                                                   const float* __restrict__ add,
                                                   const float* __restrict__ w,
                                                   float* __restrict__ xffn,
                                                   short* __restrict__ xf) {
    int row = blockIdx.x, t = threadIdx.x;
    long long i = (long long)row * 256 + t;
    const long long S4 = (long long)TOKENS * DIM / 4;
    float4 s = ((const float4*)add)[i];
    #pragma unroll
    for (int c = 0; c < 4; ++c) {
        float4 p = ((const float4*)slices)[c * S4 + i];
        s.x += p.x; s.y += p.y; s.z += p.z; s.w += p.w;
    }
    ((float4*)xffn)[i] = s;
    float ss = s.x*s.x + s.y*s.y + s.z*s.z + s.w*s.w;
    #pragma unroll
    for (int off = 32; off; off >>= 1) ss += __shfl_down(ss, off);
    __shared__ float warps[4];
    if ((t & 63) == 0) warps[t >> 6] = ss;
    __syncthreads();
    float tot = warps[0] + warps[1] + warps[2] + warps[3];
    float scale = rsqrtf(tot / (float)DIM + EPS_);
    float4 wv = ((const float4*)w)[t];
    short4 o;
    o.x = f2bf(s.x * scale * wv.x);
    o.y = f2bf(s.y * scale * wv.y);
    o.z = f2bf(s.z * scale * wv.z);
    o.w = f2bf(s.w * scale * wv.w);
    ((short4*)(xf + (long long)row * DIM))[t] = o;
}

// ---------------- QKV post (bf16 qkv): split heads, l2norm(q,k), RoPE -> bf16 [h][s][64] ----
__global__ __launch_bounds__(256) void qkv_post(const short* __restrict__ qkv,
                                                short* __restrict__ q,
                                                short* __restrict__ k) {
    int lane = threadIdx.x & 63;
    int sh = blockIdx.x * 4 + (threadIdx.x >> 6);
    int s = sh >> 4;
    int h = sh & 15;
    const short* base = qkv + (long long)s * 3 * DIM;
    float qv = bf2f(base[h * HEADDIM + lane]);
    float kv = bf2f(base[DIM + h * HEADDIM + lane]);
    float qs = qv * qv, ks = kv * kv;
    #pragma unroll
    for (int off = 32; off; off >>= 1) {
        qs += __shfl_xor(qs, off);
        ks += __shfl_xor(ks, off);
    }
    qv /= fmaxf(sqrtf(qs), EPS_);
    kv /= fmaxf(sqrtf(ks), EPS_);
    int i = lane & 31;
    float f = (float)s * powf(10000.0f, -(float)i / 32.0f);
    float c = cosf(f), sn = sinf(f);
    float qo = __shfl_xor(qv, 32);
    float ko = __shfl_xor(kv, 32);
    float sgn = (lane < 32) ? sn : -sn;
    float qr = qv * c + qo * sgn;
    float kr = kv * c + ko * sgn;
    long long o = ((long long)h * TOKENS + s) * HEADDIM + lane;
    q[o] = f2bf(qr);
    k[o] = f2bf(kr);
}

// ---------------- V transpose (bf16 qkv): [s][3D] -> vt bf16 [h][64][2048] ----------------
__global__ __launch_bounds__(256) void vtrans(const short* __restrict__ qkv,
                                              short* __restrict__ vt) {
    int h = blockIdx.z;
    int s0 = blockIdx.x * 32, d0 = blockIdx.y * 32;
    __shared__ short t[32][34];
    int tx = threadIdx.x & 31, ty = threadIdx.x >> 5;
    #pragma unroll
    for (int r = ty; r < 32; r += 8)
        t[r][tx] = qkv[(long long)(s0 + r) * (3 * DIM) + 2 * DIM + h * HEADDIM + d0 + tx];
    __syncthreads();
    #pragma unroll
    for (int r = ty; r < 32; r += 8)
        vt[((long long)h * HEADDIM + d0 + r) * TOKENS + s0 + tx] = t[tx][r];
}

// ---------------- MFMA flash attention: LDS-staged K/V (DMA), key-split combine ----------
#define PLD 68
__global__ __launch_bounds__(256) void attn_kernel(const short* __restrict__ q,
                                                   const short* __restrict__ k,
                                                   const short* __restrict__ vt,
                                                   float* __restrict__ Oacc,
                                                   float* __restrict__ lacc) {
    const int w = threadIdx.x >> 6, lane = threadIdx.x & 63;
    const int col = lane & 15, quad = lane >> 4;
    const int head = blockIdx.x / 80;
    const int t = blockIdx.x % 80;
    int qb, ch;
    if (t < 8)       { qb = t;                ch = 0; }
    else if (t < 24) { qb = 8 + (t - 8) / 2;  ch = (t - 8) % 2; }
    else if (t < 48) { qb = 16 + (t - 24) / 3; ch = (t - 24) % 3; }
    else             { qb = 24 + (t - 48) / 4; ch = (t - 48) % 4; }
    const int nch = qb / 8 + 1;
    const int ntk = qb + 1;
    const int per = (ntk + nch - 1) / nch;
    const int t0 = ch * per;
    const int t1 = (t0 + per < ntk) ? t0 + per : ntk;
    const int qbase = qb * 64 + w * 16;
    __shared__ short Ks[64 * 64];
    __shared__ short Vs[64 * 64];
    __shared__ short Ps[4 * 16 * PLD];
    short* Pw = Ps + w * 16 * PLD;
    const short* kh = k + (long long)head * TOKENS * HEADDIM;
    const short* vh = vt + (long long)head * HEADDIM * TOKENS;
    const int r8 = lane >> 3;
    const int sw = ((lane & 7) ^ r8) * 8;
    bf8 qf[2];
    #pragma unroll
    for (int ks = 0; ks < 2; ++ks)
        qf[ks] = *(const bf8*)(q + ((long long)head * TOKENS + qbase + col) * HEADDIM + ks * 32 + quad * 8);
    const int fo0 = (((0 * 4) + quad) ^ (col & 7)) * 8;
    const int fo1 = (((1 * 4) + quad) ^ (col & 7)) * 8;
    f32x4 o_[4];
    float l_[4];
    #pragma unroll
    for (int n = 0; n < 4; ++n) { f32x4 z = {0.f, 0.f, 0.f, 0.f}; o_[n] = z; }
    #pragma unroll
    for (int r = 0; r < 4; ++r) l_[r] = 0.f;
    for (int kt = t0; kt < t1; ++kt) {
        const int j0 = kt * 64;
        #pragma unroll
        for (int c = 0; c < 2; ++c) {
            int row = w * 16 + c * 8 + r8;
            async16(kh + (long long)(j0 + row) * HEADDIM + sw, Ks + (w * 16 + c * 8) * 64 + lane * 8);
            async16(vh + (long long)row * TOKENS + j0 + sw, Vs + (w * 16 + c * 8) * 64 + lane * 8);
        }
        __syncthreads();
        f32x4 sacc[4];
        #pragma unroll
        for (int n = 0; n < 4; ++n) { f32x4 z = {0.f, 0.f, 0.f, 0.f}; sacc[n] = z; }
        #pragma unroll
        for (int ks = 0; ks < 2; ++ks) {
            const int fo = ks ? fo1 : fo0;
            #pragma unroll
            for (int nt = 0; nt < 4; ++nt) {
                bf8 kf = *(const bf8*)(Ks + (nt * 16 + col) * 64 + fo);
                sacc[nt] = __builtin_amdgcn_mfma_f32_16x16x32_bf16(qf[ks], kf, sacc[nt], 0, 0, 0);
            }
        }
        const bool diag = (j0 + 64 > qbase);
        #pragma unroll
        for (int nt = 0; nt < 4; ++nt)
            #pragma unroll
            for (int r = 0; r < 4; ++r) {
                float p = __expf(sacc[nt][r] * 0.125f);
                if (diag && (j0 + nt * 16 + col > qbase + quad * 4 + r)) p = 0.f;
                l_[r] += p;
                Pw[(quad * 4 + r) * PLD + nt * 16 + col] = f2bf(p);
            }
        #pragma unroll
        for (int ks = 0; ks < 2; ++ks) {
            bf8 pf = *(const bf8*)(Pw + col * PLD + ks * 32 + quad * 8);
            const int fo = ks ? fo1 : fo0;
            #pragma unroll
            for (int nt = 0; nt < 4; ++nt) {
                bf8 vf = *(const bf8*)(Vs + (nt * 16 + col) * 64 + fo);
                o_[nt] = __builtin_amdgcn_mfma_f32_16x16x32_bf16(pf, vf, o_[nt], 0, 0, 0);
            }
        }
        __syncthreads();
    }
    float* Oc = Oacc + (long long)ch * (TOKENS * DIM);
    #pragma unroll
    for (int r = 0; r < 4; ++r) {
        int row = qbase + quad * 4 + r;
        float* op = Oc + (long long)row * DIM + head * HEADDIM;
        #pragma unroll
        for (int nt = 0; nt < 4; ++nt)
            op[nt * 16 + col] = o_[nt][r];
        float l = l_[r];
        #pragma unroll
        for (int off = 1; off < 16; off <<= 1) l += __shfl_xor(l, off);
        if (col == 0) lacc[ch * (TOKENS * NHEADS) + row * NHEADS + head] = l;
    }
}

// ---------------- Attention normalize: xo = sum_ch Oacc / sum_ch l -> bf16 ----------------
__global__ void attn_norm(const float* __restrict__ Oacc, const float* __restrict__ lacc,
                          short* __restrict__ xo) {
    long long i = (long long)blockIdx.x * 256 + threadIdx.x;  // 2M
    int row = (int)(i >> 10), col = (int)(i & 1023);
    int nch = (row >> 9) + 1;
    int head = col >> 6;
    float so = 0.f, sl = 0.f;
    for (int c = 0; c < nch; ++c) {
        so += Oacc[(long long)c * (TOKENS * DIM) + i];
        sl += lacc[c * (TOKENS * NHEADS) + row * NHEADS + head];
    }
    xo[i] = f2bf(so / sl);
}

// ---------------- Router (bf16 x input) ----------------
__global__ __launch_bounds__(256) void router_kernel(const short* __restrict__ xf,
                                                     const float* __restrict__ keys_w,
                                                     const int* __restrict__ idx,
                                                     const float* __restrict__ vals,
                                                     float* __restrict__ w_route) {
    int t = blockIdx.x;
    int tid = threadIdx.x;
    int e = tid & 31, c = tid >> 5;
    const short* xr = xf + (long long)t * DIM;
    float p = 0.f;
    for (int j = 0; j < 128; ++j)
        p += bf2f(xr[c * 128 + j]) * keys_w[(c * 128 + j) * NEXP + e];
    __shared__ float part[8][32];
    part[c][e] = p;
    __syncthreads();
    if (tid < NEXP) {
        float lg = 0.f;
        #pragma unroll
        for (int cc = 0; cc < 8; ++cc) lg += part[cc][tid];
        part[0][tid] = lg;
    }
    __syncthreads();
    __shared__ float gate_s[TOPK];
    __shared__ int idx_s[TOPK];
    if (tid < TOPK) {
        int ii = idx[t * TOPK + tid];
        float g = vals[t * TOPK + tid] + part[0][ii];
        gate_s[tid] = (1.0f / (1.0f + __expf(-g))) * RSF_;
        idx_s[tid] = ii;
    }
    __syncthreads();
    if (tid < NEXP) {
        float wr = 0.f;
        #pragma unroll
        for (int kk = 0; kk < TOPK; ++kk)
            if (idx_s[kk] == tid) wr += gate_s[kk];
        w_route[(long long)t * NEXP + tid] = wr;
    }
}

extern "C" void kernel_launch(void* const* d_in, const int* in_sizes, int n_in,
                              void* d_out, int out_size, void* d_ws, size_t ws_size,
                              hipStream_t stream) {
    (void)in_sizes; (void)n_in; (void)out_size; (void)ws_size;
    const float* x_input     = (const float*)d_in[0];
    const int*   indices     = (const int*)d_in[1];
    const float* values      = (const float*)d_in[2];
    const float* w_attn      = (const float*)d_in[3];
    const float* w_attn_o    = (const float*)d_in[4];
    const float* attn_norm_w = (const float*)d_in[5];
    const float* ffn_norm_w  = (const float*)d_in[6];
    const float* ffn_experts = (const float*)d_in[7];
    const float* keys_w      = (const float*)d_in[8];
    const float* w_up        = (const float*)d_in[9];
    const float* w_down      = (const float*)d_in[10];
    float* out = (float*)d_out;
    float* ws  = (float*)d_ws;

    const long long M1 = 1024 * 1024;
    const long long SLICE = (long long)TOKENS * DIM;  // 2M floats
    // Workspace map, M1-float units, TRUE extents. Phase-disjoint liveness audited:
    //   phase A:  xa[2,3) xattn[4,5) Oacc/oslice[6,14) lacc[14,14.13) qh[15,16)
    //             kh[16,17) vt[17,18) wattn_t[18,19.5) wattno[19.5,20) qkv[21,24)
    //   phase B/C (after combine_rms): wdownt[2,3) wupt[4,6) wgu[6,10) hs[8,10 after
    //             gemm_act<true>) h[10,14) w2t[14,16) yslice[16,24) w_route[20,20.07)
    //   whole call: xffn[0,2) xf[3,4)
    float* xffn    = ws + 0 * M1;                     // [0,2)    fp32
    short* xa_bf   = (short*)(ws + 2 * M1);           // [2,3)    phase A
    short* wdownt  = (short*)(ws + 2 * M1);           // [2,3)    phase B/C (xa dead)
    short* xf_bf   = (short*)(ws + 3 * M1);           // [3,4)
    short* xattn_bf= (short*)(ws + 4 * M1);           // [4,5)    phase A
    short* wupt    = (short*)(ws + 4 * M1);           // [4,6)    phase B/C (xattn dead)
    float* Oacc    = ws + 6 * M1;                     // [6,14)   phase A
    float* lacc    = ws + 14 * M1;                    // [14,14.13) phase A
    short* qh_bf   = (short*)(ws + 15 * M1);          // [15,16)  phase A
    short* kh_bf   = (short*)(ws + 16 * M1);          // [16,17)  phase A
    short* vt_bf   = (short*)(ws + 17 * M1);          // [17,18)  phase A
    short* wattn_t = (short*)(ws + 18 * M1);          // [18,19.5) phase A
    short* wattno_t= (short*)(ws + 19 * M1 + M1 / 2); // [19.5,20) phase A
    float* w_route = ws + 20 * M1;                    // [20,20.07) phase B ([20,21) unused in A)
    short* qkv_bf  = (short*)(ws + 21 * M1);          // [21,24)  dead after vtrans
    float* oslice  = ws + 6 * M1;                     // [6,14)   (Oacc dead after attn_norm)
    short* wgu     = (short*)(ws + 6 * M1);           // [6,10)   phase B (oslice dead)
    short* hs_bf   = (short*)(ws + 8 * M1);           // [8,10)   written after wgu dead
    short* h_bf    = (short*)(ws + 10 * M1);          // [10,14)
    short* w2t     = (short*)(ws + 14 * M1);          // [14,16)  (lacc, qh dead)
    float* yslice  = ws + 16 * M1;                    // [16,24)  (kh/vt/wattn/wattno/qkv dead)

    // ---- phase A: attention ----
    tconv<<<dim3(3072 / 32, DIM / 32, 1), 256, 0, stream>>>(w_attn, 0, wattn_t, 0, DIM, 3 * DIM);
    rmsnorm_kernel<<<TOKENS, 256, 0, stream>>>(x_input, attn_norm_w, xa_bf);
    gemm_bf16<2><<<dim3(3072 / 128, TOKENS / 128, 1), 256, 0, stream>>>(
        xa_bf, DIM, 0, wattn_t, DIM, 0, qkv_bf, 3 * DIM, 0, TOKENS, 3 * DIM, DIM);
    qkv_post<<<(TOKENS * NHEADS) / 4, 256, 0, stream>>>(qkv_bf, qh_bf, kh_bf);
    vtrans<<<dim3(TOKENS / 32, HEADDIM / 32, NHEADS), 256, 0, stream>>>(qkv_bf, vt_bf);
    attn_kernel<<<NHEADS * 80, 256, 0, stream>>>(qh_bf, kh_bf, vt_bf, Oacc, lacc);
    attn_norm<<<(TOKENS * DIM) / 256, 256, 0, stream>>>(Oacc, lacc, xattn_bf);
    tconv<<<dim3(DIM / 32, DIM / 32, 1), 256, 0, stream>>>(w_attn_o, 0, wattno_t, 0, DIM, DIM);
    gemm_bf16<3><<<dim3(DIM / 128, TOKENS / 128, 4), 256, 0, stream>>>(
        xattn_bf, DIM, 0, wattno_t, DIM, 0, oslice, DIM, SLICE, TOKENS, DIM, DIM);
    // xffn = x_input + sum(oslice); xf_bf = rmsnorm(xffn) -- fused
    combine_rms<<<TOKENS, 256, 0, stream>>>(oslice, x_input, ffn_norm_w, xffn, xf_bf);

    // ---- phase B/C: all weight conversions in ONE launch, then router + GEMMs ----
    wconv_merged<<<30720, 256, 0, stream>>>(ffn_experts, w_up, w_down,
                                            wgu, w2t, wupt, wdownt);
    router_kernel<<<TOKENS, 256, 0, stream>>>(xf_bf, keys_w, indices, values, w_route);
    gemm_act<true, true><<<dim3(1, TOKENS / 64, NEXP), 256, 0, stream>>>(
        xf_bf, DIM, wgu, 256 * 1024, h_bf, NEXP * EDIM, w_route);
    gemm_bf16<3><<<dim3(DIM / 128, TOKENS / 128, 4), 256, 0, stream>>>(
        h_bf, NEXP * EDIM, 0, w2t, NEXP * EDIM, 0, yslice, DIM, SLICE, TOKENS, DIM, NEXP * EDIM);
    gemm_act<false, false><<<dim3((2 * DSHARED) / 256, TOKENS / 64, 1), 256, 0, stream>>>(
        xf_bf, DIM, wupt, 0, hs_bf, DSHARED, nullptr);
    gemm_bf16<4><<<dim3(DIM / 128, TOKENS / 128, 4), 256, 0, stream>>>(
        hs_bf, DSHARED, 0, wdownt, DSHARED, 0, yslice, DIM, SLICE, TOKENS, DIM, DSHARED);

    // ---- final: out = xffn + sum of 4 slices ----
    combine4<<<(TOKENS * DIM) / 1024, 256, 0, stream>>>(yslice, xffn, out);
}